// Round 2
// baseline (299.189 us; speedup 1.0000x reference)
//
#include <hip/hip_runtime.h>
#include <stdint.h>

// ---------------- types ----------------
typedef short bf16x8 __attribute__((ext_vector_type(8)));
typedef float f32x4  __attribute__((ext_vector_type(4)));

__device__ __forceinline__ uint16_t f2bf(float f) {
    uint32_t u = __float_as_uint(f);
    u += 0x7FFF + ((u >> 16) & 1);   // round-to-nearest-even
    return (uint16_t)(u >> 16);
}
__device__ __forceinline__ uint32_t pk2bf(float a, float b) {
    return (uint32_t)f2bf(a) | ((uint32_t)f2bf(b) << 16);
}

// ---------------- prologue: fp32 -> bf16 transposed weights ----------------
// out[e][c][r] = bf16(in[e][r][c]);  in: [E][R][C] fp32, out: [E][C][R] bf16
__global__ void transpose_bf16(const float* __restrict__ in, uint16_t* __restrict__ out,
                               int R, int C) {
    __shared__ float t[32][33];
    const int tx = threadIdx.x, ty = threadIdx.y;
    const int r0 = blockIdx.y * 32, c0 = blockIdx.x * 32;
    const float* ine = in + (size_t)blockIdx.z * R * C;
    uint16_t* oute   = out + (size_t)blockIdx.z * R * C;
#pragma unroll
    for (int j = 0; j < 4; ++j)
        t[ty + 8 * j][tx] = ine[(size_t)(r0 + ty + 8 * j) * C + (c0 + tx)];
    __syncthreads();
#pragma unroll
    for (int j = 0; j < 4; ++j) {
        int orow = c0 + ty + 8 * j;   // output row = input col
        int ocol = r0 + tx;           // output col = input row
        oute[(size_t)orow * R + ocol] = f2bf(t[tx][ty + 8 * j]);
    }
}

// ---------------- prologue: X fp32 -> bf16 (row-major, k-contiguous) -------
__global__ void cvt_bf16(const float* __restrict__ in, uint16_t* __restrict__ out, int n4) {
    const int i = blockIdx.x * blockDim.x + threadIdx.x;
    if (i < n4) {
        const float4 v = ((const float4*)in)[i];
        ushort4 h;
        h.x = f2bf(v.x); h.y = f2bf(v.y); h.z = f2bf(v.z); h.w = f2bf(v.w);
        ((ushort4*)out)[i] = h;
    }
}

// ---------------- fused ensemble MLP (swapped-operand MFMA) ----------------
// All layers: D = mfma(A=W^T fragment [n][k], B=activation fragment [b][k]).
// D layout: col(lane&15) = batch row, rows(kg*4+j) = 4 consecutive output cols
// -> epilogue writes are 8B row-contiguous; next layer's B-read matches.
//
// LDS: single 64KB h-buffer, [64 rows][512 cols] bf16, XOR-swizzled:
//   byte(row,colbyte) = row*1024 + (colbyte ^ ((row&7)<<4))

template <int K, bool RELU, bool B_LDS, bool SYNC_BEFORE_EPI>
__device__ __forceinline__ void layer64(
    const uint16_t* __restrict__ Aw,    // W^T + (e*512 + n0)*K  (wave's 64 n-rows)
    const uint16_t* __restrict__ Bg,    // activations global [64][K] (if !B_LDS)
    const char* __restrict__ Bl,        // LDS activations (if B_LDS), stride 1024B
    const float* __restrict__ bias,     // bias + e*512 + n0
    char* __restrict__ ldsOut,          // may alias Bl (SYNC_BEFORE_EPI guards)
    int n0, int kg, int lr) {

    f32x4 acc[4][4];
#pragma unroll
    for (int m = 0; m < 4; ++m)
#pragma unroll
        for (int n = 0; n < 4; ++n) acc[m][n] = f32x4{0.f, 0.f, 0.f, 0.f};

    auto ldA = [&](int mf, int k0) -> bf16x8 {
        return *(const bf16x8*)(Aw + (size_t)(mf * 16 + lr) * K + k0 + kg * 8);
    };
    auto ldB = [&](int nf, int k0) -> bf16x8 {
        if constexpr (B_LDS) {
            const int row = nf * 16 + lr;
            return *(const bf16x8*)(Bl + row * 1024 +
                                    ((((k0 + kg * 8) << 1)) ^ ((row & 7) << 4)));
        } else {
            return *(const bf16x8*)(Bg + (size_t)(nf * 16 + lr) * K + k0 + kg * 8);
        }
    };

    bf16x8 a0[4], b0[4], a1[4], b1[4];
#pragma unroll
    for (int i = 0; i < 4; ++i) { a0[i] = ldA(i, 0); b0[i] = ldB(i, 0); }

#pragma unroll
    for (int k0 = 0; k0 < K; k0 += 64) {   // K in {256,512}
#pragma unroll
        for (int i = 0; i < 4; ++i) { a1[i] = ldA(i, k0 + 32); b1[i] = ldB(i, k0 + 32); }
#pragma unroll
        for (int m = 0; m < 4; ++m)
#pragma unroll
            for (int n = 0; n < 4; ++n)
                acc[m][n] = __builtin_amdgcn_mfma_f32_16x16x32_bf16(a0[m], b0[n], acc[m][n], 0, 0, 0);
        if (k0 + 64 < K) {
#pragma unroll
            for (int i = 0; i < 4; ++i) { a0[i] = ldA(i, k0 + 64); b0[i] = ldB(i, k0 + 64); }
        }
#pragma unroll
        for (int m = 0; m < 4; ++m)
#pragma unroll
            for (int n = 0; n < 4; ++n)
                acc[m][n] = __builtin_amdgcn_mfma_f32_16x16x32_bf16(a1[m], b1[n], acc[m][n], 0, 0, 0);
    }

    if (SYNC_BEFORE_EPI) __syncthreads();   // all waves done READING Bl

    // epilogue: bias + (relu) + pack 4 bf16 -> one 8B swizzled LDS write / frag
#pragma unroll
    for (int mf = 0; mf < 4; ++mf) {
        const float4 bv = *(const float4*)(bias + mf * 16 + kg * 4);
#pragma unroll
        for (int nf = 0; nf < 4; ++nf) {
            float x0 = acc[mf][nf][0] + bv.x;
            float x1 = acc[mf][nf][1] + bv.y;
            float x2 = acc[mf][nf][2] + bv.z;
            float x3 = acc[mf][nf][3] + bv.w;
            if (RELU) {
                x0 = fmaxf(x0, 0.f); x1 = fmaxf(x1, 0.f);
                x2 = fmaxf(x2, 0.f); x3 = fmaxf(x3, 0.f);
            }
            uint2 w;
            w.x = pk2bf(x0, x1);
            w.y = pk2bf(x2, x3);
            const int row = nf * 16 + lr;
            const int colbyte = (n0 + mf * 16 + kg * 4) << 1;
            *(uint2*)(ldsOut + row * 1024 + (colbyte ^ ((row & 7) << 4))) = w;
        }
    }
}

__global__ __launch_bounds__(512, 4) void fused_mlp(
    const uint16_t* __restrict__ Xbf,
    const uint16_t* __restrict__ W1T, const float* __restrict__ b1,
    const uint16_t* __restrict__ W2T, const float* __restrict__ b2,
    const uint16_t* __restrict__ W3T, const float* __restrict__ b3,
    float* __restrict__ out) {
    extern __shared__ char hbuf[];   // 64KB: [64][512] bf16 swizzled
    const int tid = threadIdx.x, wid = tid >> 6, lane = tid & 63;
    const int kg = lane >> 4, lr = lane & 15;
    const int e  = blockIdx.x & 7;          // XCD round-robin -> per-XCD weight locality
    const int b0 = (blockIdx.x >> 3) * 64;  // row block
    const int n0 = wid * 64;                // wave's output-column block (layers 1,2)

    // ---- layer 1: h1 = relu(X @ W1 + b1), K=256, B from global bf16 X ----
    layer64<256, true, false, false>(W1T + ((size_t)e * 512 + n0) * 256,
                                     Xbf + (size_t)b0 * 256, nullptr,
                                     b1 + e * 512 + n0, hbuf, n0, kg, lr);
    __syncthreads();

    // ---- layer 2: h2 = relu(h1 @ W2 + b2), K=512, B from LDS (in-place) ----
    layer64<512, true, true, true>(W2T + ((size_t)e * 512 + n0) * 512,
                                   nullptr, hbuf,
                                   b2 + e * 512 + n0, hbuf, n0, kg, lr);
    __syncthreads();

    // ---- layer 3: out = h2 @ W3 + b3  (64b x 32n, K=512) ----
    {
        const int c3  = wid >> 2;   // 0..1 : n-group (16 cols each)
        const int bf3 = wid & 3;    // 0..3 : b-group (16 rows each)
        const uint16_t* A = W3T + (size_t)e * 32 * 512 + (size_t)(c3 * 16 + lr) * 512;
        const int rowB  = bf3 * 16 + lr;
        const int bbyte = rowB * 1024;
        const int bswz  = (rowB & 7) << 4;
        f32x4 acc = f32x4{0.f, 0.f, 0.f, 0.f};
#pragma unroll
        for (int k0 = 0; k0 < 512; k0 += 32) {
            bf16x8 a = *(const bf16x8*)(A + k0 + kg * 8);
            bf16x8 b = *(const bf16x8*)(hbuf + bbyte + ((((k0 + kg * 8) << 1)) ^ bswz));
            acc = __builtin_amdgcn_mfma_f32_16x16x32_bf16(a, b, acc, 0, 0, 0);
        }
        const float4 bv = *(const float4*)(b3 + e * 32 + c3 * 16 + kg * 4);
        const int ob = b0 + bf3 * 16 + lr;
        float4 res;
        res.x = acc[0] + bv.x; res.y = acc[1] + bv.y;
        res.z = acc[2] + bv.z; res.w = acc[3] + bv.w;
        *(float4*)(out + (size_t)ob * 256 + e * 32 + c3 * 16 + kg * 4) = res;
    }
}

// ---------------- host launch ----------------
extern "C" void kernel_launch(void* const* d_in, const int* in_sizes, int n_in,
                              void* d_out, int out_size, void* d_ws, size_t ws_size,
                              hipStream_t stream) {
    const float* X  = (const float*)d_in[0];   // [16384,256]
    const float* W1 = (const float*)d_in[1];   // [8,256,512]
    const float* b1 = (const float*)d_in[2];   // [8,512]
    const float* W2 = (const float*)d_in[3];   // [8,512,512]
    const float* b2 = (const float*)d_in[4];   // [8,512]
    const float* W3 = (const float*)d_in[5];   // [8,512,32]
    const float* b3 = (const float*)d_in[6];   // [8,32]
    float* out = (float*)d_out;                // [16384,8,32]

    uint16_t* w1t = (uint16_t*)d_ws;           // [8][512][256] bf16  (2 MB)
    uint16_t* w2t = w1t + 8 * 256 * 512;       // [8][512][512] bf16  (4 MB)
    uint16_t* w3t = w2t + 8 * 512 * 512;       // [8][32][512]  bf16  (256 KB)
    uint16_t* xbf = w3t + 8 * 512 * 32;        // [16384][256]  bf16  (8 MB)

    dim3 blk(32, 8);
    transpose_bf16<<<dim3(512 / 32, 256 / 32, 8), blk, 0, stream>>>(W1, w1t, 256, 512);
    transpose_bf16<<<dim3(512 / 32, 512 / 32, 8), blk, 0, stream>>>(W2, w2t, 512, 512);
    transpose_bf16<<<dim3(32 / 32, 512 / 32, 8),  blk, 0, stream>>>(W3, w3t, 512, 32);
    cvt_bf16<<<4096, 256, 0, stream>>>(X, xbf, 16384 * 256 / 4);

    (void)hipFuncSetAttribute((const void*)fused_mlp,
                              hipFuncAttributeMaxDynamicSharedMemorySize, 65536);
    fused_mlp<<<2048, 512, 65536, stream>>>(xbf, w1t, b1, w2t, b2, w3t, b3, out);
}

// Round 3
// 261.116 us; speedup vs baseline: 1.1458x; 1.1458x over previous
//
#include <hip/hip_runtime.h>
#include <stdint.h>

// ---------------- types ----------------
typedef short bf16x8 __attribute__((ext_vector_type(8)));
typedef float f32x4  __attribute__((ext_vector_type(4)));

__device__ __forceinline__ uint16_t f2bf(float f) {
    uint32_t u = __float_as_uint(f);
    u += 0x7FFF + ((u >> 16) & 1);   // round-to-nearest-even
    return (uint16_t)(u >> 16);
}
__device__ __forceinline__ uint32_t pk2bf(float a, float b) {
    return (uint32_t)f2bf(a) | ((uint32_t)f2bf(b) << 16);
}

// ---------------- prologue: fp32 -> bf16 transposed weights ----------------
// out[e][c][r] = bf16(in[e][r][c]);  in: [E][R][C] fp32, out: [E][C][R] bf16
__global__ void transpose_bf16(const float* __restrict__ in, uint16_t* __restrict__ out,
                               int R, int C) {
    __shared__ float t[32][33];
    const int tx = threadIdx.x, ty = threadIdx.y;
    const int r0 = blockIdx.y * 32, c0 = blockIdx.x * 32;
    const float* ine = in + (size_t)blockIdx.z * R * C;
    uint16_t* oute   = out + (size_t)blockIdx.z * R * C;
#pragma unroll
    for (int j = 0; j < 4; ++j)
        t[ty + 8 * j][tx] = ine[(size_t)(r0 + ty + 8 * j) * C + (c0 + tx)];
    __syncthreads();
#pragma unroll
    for (int j = 0; j < 4; ++j) {
        int orow = c0 + ty + 8 * j;
        int ocol = r0 + tx;
        oute[(size_t)orow * R + ocol] = f2bf(t[tx][ty + 8 * j]);
    }
}

// ---------------- prologue: X fp32 -> bf16 ----------------
__global__ void cvt_bf16(const float* __restrict__ in, uint16_t* __restrict__ out, int n4) {
    const int i = blockIdx.x * blockDim.x + threadIdx.x;
    if (i < n4) {
        const float4 v = ((const float4*)in)[i];
        ushort4 h;
        h.x = f2bf(v.x); h.y = f2bf(v.y); h.z = f2bf(v.z); h.w = f2bf(v.w);
        ((ushort4*)out)[i] = h;
    }
}

// ---------------- fused ensemble MLP ----------------
// Block: 256 threads = 4 waves. BM=64 batch rows. Layers 1/2: swapped MFMA
// D = mfma(A=W^T frag [n][k], B=act frag [b][k]); wave owns 128 n-cols
// (8 m-frags) x 64 b-rows (4 b-frags) -> acc 8x4 frags = 128 f32 regs.
// D: col(lane&15)=batch row, rows(kg*4+j)=4 consecutive out cols -> 8B LDS writes.
// LDS: single 64KB h buffer [64][512] bf16, XOR-swizzle byte^=((row&7)<<4).

template <int K, bool B_LDS>
__device__ __forceinline__ void layer128(
    const uint16_t* __restrict__ Aw,    // W^T + (e*512 + n0)*K
    const uint16_t* __restrict__ Bg,    // global activations [64][K] (if !B_LDS)
    const char* __restrict__ Bl,        // LDS activations (if B_LDS)
    const float* __restrict__ bias,     // bias + e*512 + n0
    char* __restrict__ ldsOut,
    int n0, int kg, int lr, bool syncBeforeEpi) {

    f32x4 acc[8][4];
#pragma unroll
    for (int m = 0; m < 8; ++m)
#pragma unroll
        for (int n = 0; n < 4; ++n) acc[m][n] = f32x4{0.f, 0.f, 0.f, 0.f};

    auto ldA = [&](int mf, int k0) -> bf16x8 {
        return *(const bf16x8*)(Aw + (size_t)(mf * 16 + lr) * K + k0 + kg * 8);
    };
    auto ldB = [&](int nf, int k0) -> bf16x8 {
        if constexpr (B_LDS) {
            const int row = nf * 16 + lr;
            return *(const bf16x8*)(Bl + row * 1024 +
                                    ((((k0 + kg * 8) << 1)) ^ ((row & 7) << 4)));
        } else {
            return *(const bf16x8*)(Bg + (size_t)(nf * 16 + lr) * K + k0 + kg * 8);
        }
    };

    bf16x8 a0[8], b0[4], a1[8], b1[4];
#pragma unroll
    for (int i = 0; i < 8; ++i) a0[i] = ldA(i, 0);
#pragma unroll
    for (int i = 0; i < 4; ++i) b0[i] = ldB(i, 0);

#pragma unroll
    for (int k0 = 0; k0 < K; k0 += 64) {   // K in {256,512}
#pragma unroll
        for (int i = 0; i < 8; ++i) a1[i] = ldA(i, k0 + 32);
#pragma unroll
        for (int i = 0; i < 4; ++i) b1[i] = ldB(i, k0 + 32);
#pragma unroll
        for (int m = 0; m < 8; ++m)
#pragma unroll
            for (int n = 0; n < 4; ++n)
                acc[m][n] = __builtin_amdgcn_mfma_f32_16x16x32_bf16(a0[m], b0[n], acc[m][n], 0, 0, 0);
        if (k0 + 64 < K) {
#pragma unroll
            for (int i = 0; i < 8; ++i) a0[i] = ldA(i, k0 + 64);
#pragma unroll
            for (int i = 0; i < 4; ++i) b0[i] = ldB(i, k0 + 64);
        }
#pragma unroll
        for (int m = 0; m < 8; ++m)
#pragma unroll
            for (int n = 0; n < 4; ++n)
                acc[m][n] = __builtin_amdgcn_mfma_f32_16x16x32_bf16(a1[m], b1[n], acc[m][n], 0, 0, 0);
    }

    if (syncBeforeEpi) __syncthreads();   // all waves done READING Bl (aliases ldsOut)

    // epilogue: bias + relu + pack 4 bf16 -> one 8B swizzled LDS write per frag
#pragma unroll
    for (int mf = 0; mf < 8; ++mf) {
        const float4 bv = *(const float4*)(bias + mf * 16 + kg * 4);
#pragma unroll
        for (int nf = 0; nf < 4; ++nf) {
            float x0 = fmaxf(acc[mf][nf][0] + bv.x, 0.f);
            float x1 = fmaxf(acc[mf][nf][1] + bv.y, 0.f);
            float x2 = fmaxf(acc[mf][nf][2] + bv.z, 0.f);
            float x3 = fmaxf(acc[mf][nf][3] + bv.w, 0.f);
            uint2 w;
            w.x = pk2bf(x0, x1);
            w.y = pk2bf(x2, x3);
            const int row = nf * 16 + lr;
            const int colbyte = (n0 + mf * 16 + kg * 4) << 1;
            *(uint2*)(ldsOut + row * 1024 + (colbyte ^ ((row & 7) << 4))) = w;
        }
    }
}

__global__ __launch_bounds__(256, 2) void fused_mlp(
    const uint16_t* __restrict__ Xbf,
    const uint16_t* __restrict__ W1T, const float* __restrict__ b1,
    const uint16_t* __restrict__ W2T, const float* __restrict__ b2,
    const uint16_t* __restrict__ W3T, const float* __restrict__ b3,
    float* __restrict__ out) {
    extern __shared__ char hbuf[];   // 64KB: [64][512] bf16 swizzled
    const int tid = threadIdx.x, wid = tid >> 6, lane = tid & 63;
    const int kg = lane >> 4, lr = lane & 15;
    const int e  = blockIdx.x & 7;          // XCD round-robin -> per-XCD weight locality
    const int b0 = (blockIdx.x >> 3) * 64;  // batch row block
    const int n0 = wid * 128;               // wave's output-column block (layers 1,2)

    // ---- layer 1: h1 = relu(X @ W1 + b1), K=256, B from global bf16 X ----
    layer128<256, false>(W1T + ((size_t)e * 512 + n0) * 256,
                         Xbf + (size_t)b0 * 256, nullptr,
                         b1 + e * 512 + n0, hbuf, n0, kg, lr, false);
    __syncthreads();

    // ---- layer 2: h2 = relu(h1 @ W2 + b2), K=512, B from LDS (in-place) ----
    layer128<512, true>(W2T + ((size_t)e * 512 + n0) * 512,
                        nullptr, hbuf,
                        b2 + e * 512 + n0, hbuf, n0, kg, lr, true);
    __syncthreads();

    // ---- layer 3: out = h2 @ W3 + b3 (64b x 32n, K=512), NON-swapped ----
    // D = mfma(A=h frag [b][k], B=W3T frag [n][k]) -> lane&15 = out col,
    // kg*4+v = batch row -> scalar stores are 64B row-contiguous.
    {
        const int rowB  = wid * 16 + lr;      // wave owns 16 batch rows
        const int bbyte = rowB * 1024;
        const int bswz  = (rowB & 7) << 4;
        const uint16_t* W3e = W3T + (size_t)e * 32 * 512;
        f32x4 acc[2];
        acc[0] = f32x4{0.f, 0.f, 0.f, 0.f};
        acc[1] = f32x4{0.f, 0.f, 0.f, 0.f};
#pragma unroll
        for (int k0 = 0; k0 < 512; k0 += 32) {
            bf16x8 a = *(const bf16x8*)(hbuf + bbyte + ((((k0 + kg * 8) << 1)) ^ bswz));
#pragma unroll
            for (int nf = 0; nf < 2; ++nf) {
                bf16x8 b = *(const bf16x8*)(W3e + (size_t)(nf * 16 + lr) * 512 + k0 + kg * 8);
                acc[nf] = __builtin_amdgcn_mfma_f32_16x16x32_bf16(a, b, acc[nf], 0, 0, 0);
            }
        }
#pragma unroll
        for (int nf = 0; nf < 2; ++nf) {
            const float bb = b3[e * 32 + nf * 16 + lr];
#pragma unroll
            for (int v = 0; v < 4; ++v) {
                const int row = b0 + wid * 16 + kg * 4 + v;
                out[(size_t)row * 256 + e * 32 + nf * 16 + lr] = acc[nf][v] + bb;
            }
        }
    }
}

// ---------------- host launch ----------------
extern "C" void kernel_launch(void* const* d_in, const int* in_sizes, int n_in,
                              void* d_out, int out_size, void* d_ws, size_t ws_size,
                              hipStream_t stream) {
    const float* X  = (const float*)d_in[0];   // [16384,256]
    const float* W1 = (const float*)d_in[1];   // [8,256,512]
    const float* b1 = (const float*)d_in[2];   // [8,512]
    const float* W2 = (const float*)d_in[3];   // [8,512,512]
    const float* b2 = (const float*)d_in[4];   // [8,512]
    const float* W3 = (const float*)d_in[5];   // [8,512,32]
    const float* b3 = (const float*)d_in[6];   // [8,32]
    float* out = (float*)d_out;                // [16384,8,32]

    uint16_t* w1t = (uint16_t*)d_ws;           // [8][512][256] bf16  (2 MB)
    uint16_t* w2t = w1t + 8 * 256 * 512;       // [8][512][512] bf16  (4 MB)
    uint16_t* w3t = w2t + 8 * 512 * 512;       // [8][32][512]  bf16  (256 KB)
    uint16_t* xbf = w3t + 8 * 512 * 32;        // [16384][256]  bf16  (8 MB)

    dim3 blk(32, 8);
    transpose_bf16<<<dim3(512 / 32, 256 / 32, 8), blk, 0, stream>>>(W1, w1t, 256, 512);
    transpose_bf16<<<dim3(512 / 32, 512 / 32, 8), blk, 0, stream>>>(W2, w2t, 512, 512);
    transpose_bf16<<<dim3(32 / 32, 512 / 32, 8),  blk, 0, stream>>>(W3, w3t, 512, 32);
    cvt_bf16<<<4096, 256, 0, stream>>>(X, xbf, 16384 * 256 / 4);

    (void)hipFuncSetAttribute((const void*)fused_mlp,
                              hipFuncAttributeMaxDynamicSharedMemorySize, 65536);
    fused_mlp<<<2048, 256, 65536, stream>>>(xbf, w1t, b1, w2t, b2, w3t, b3, out);
}

// Round 6
// 213.605 us; speedup vs baseline: 1.4007x; 1.2224x over previous
//
#include <hip/hip_runtime.h>
#include <stdint.h>

// ---------------- types ----------------
typedef short bf16x8 __attribute__((ext_vector_type(8)));
typedef float f32x4  __attribute__((ext_vector_type(4)));

__device__ __forceinline__ uint16_t f2bf(float f) {
    uint32_t u = __float_as_uint(f);
    u += 0x7FFF + ((u >> 16) & 1);   // round-to-nearest-even
    return (uint16_t)(u >> 16);
}
__device__ __forceinline__ uint32_t pk2bf(float a, float b) {
    return (uint32_t)f2bf(a) | ((uint32_t)f2bf(b) << 16);
}

typedef __attribute__((address_space(1))) const uint32_t gu32;
typedef __attribute__((address_space(3))) uint32_t lu32;
__device__ __forceinline__ void gload16(const void* g, void* l) {
    // async global->LDS, 16B/lane; LDS dest = wave-uniform base + lane*16 (m104/m108)
    __builtin_amdgcn_global_load_lds((gu32*)g, (lu32*)l, 16, 0, 0);
}

// ---------------- prologue: fp32 -> bf16 transposed weights ----------------
__global__ void transpose_bf16(const float* __restrict__ in, uint16_t* __restrict__ out,
                               int R, int C) {
    __shared__ float t[32][33];
    const int tx = threadIdx.x, ty = threadIdx.y;
    const int r0 = blockIdx.y * 32, c0 = blockIdx.x * 32;
    const float* ine = in + (size_t)blockIdx.z * R * C;
    uint16_t* oute   = out + (size_t)blockIdx.z * R * C;
#pragma unroll
    for (int j = 0; j < 4; ++j)
        t[ty + 8 * j][tx] = ine[(size_t)(r0 + ty + 8 * j) * C + (c0 + tx)];
    __syncthreads();
#pragma unroll
    for (int j = 0; j < 4; ++j) {
        int orow = c0 + ty + 8 * j;
        int ocol = r0 + tx;
        oute[(size_t)orow * R + ocol] = f2bf(t[tx][ty + 8 * j]);
    }
}

__global__ void cvt_bf16(const float* __restrict__ in, uint16_t* __restrict__ out, int n4) {
    const int i = blockIdx.x * blockDim.x + threadIdx.x;
    if (i < n4) {
        const float4 v = ((const float4*)in)[i];
        ushort4 h;
        h.x = f2bf(v.x); h.y = f2bf(v.y); h.z = f2bf(v.z); h.w = f2bf(v.w);
        ((ushort4*)out)[i] = h;
    }
}

// =====================================================================
// m97-exact GEMM, 128x128 tile, BK=64, 4 waves, LDS single-buffered via
// global_load_lds, linear dest AND source (no swizzle). Activations and
// outputs are E-INDEXED via strides (round-4/5 bug: all 8 ensembles
// raced on one un-e-indexed h buffer).
// Swapped MFMA: D = mfma(A=W frag [n][k], B=act frag [m][k])
//   -> D col(lane&15)=batch row, row(kg*4+v)=out col.
// =====================================================================
template <int K>
__global__ __launch_bounds__(256, 3) void gemm_h(
    const uint16_t* __restrict__ Act,   // activations, + e*actEStride, [Mc][K]
    size_t actEStride,                  // 0 when activations shared across e (layer 1)
    const uint16_t* __restrict__ Wt,    // [8][512][K] bf16 (n-major, k-contig)
    const float* __restrict__ bias,     // [8][512]
    uint16_t* __restrict__ Out,         // + e*outEStride, [Mc][512] bf16 (relu'd)
    size_t outEStride)
{
    __shared__ char smem[32768];        // [0,16K): W tile [128][64k]; [16K,32K): Act tile
    const int tid = threadIdx.x, wid = tid >> 6, lane = tid & 63;
    const int kg = lane >> 4, lr = lane & 15;
    const int e   = blockIdx.x;         // 0..7 -> XCD round-robin pins e's weights/slabs
    const int nb0 = blockIdx.y * 128;
    const int m0  = blockIdx.z * 128;   // chunk-relative batch row
    const int wr = wid >> 1, wc = wid & 1;

    const uint16_t* Wbase = Wt  + ((size_t)e * 512 + nb0) * K;
    const uint16_t* Abase = Act + (size_t)e * actEStride + (size_t)m0 * K;
    uint16_t* Obase       = Out + (size_t)e * outEStride;

    f32x4 acc[4][4];
#pragma unroll
    for (int m = 0; m < 4; ++m)
#pragma unroll
        for (int n = 0; n < 4; ++n) acc[m][n] = f32x4{0.f, 0.f, 0.f, 0.f};

    const int rlo = lane >> 3, pslot = lane & 7;   // staging lane map (linear)

    for (int ks = 0; ks < K; ks += 64) {
        // ---- stage both tiles: 4 x 1KB segments per wave per tile ----
#pragma unroll
        for (int i = 0; i < 4; ++i) {
            const int g   = wid * 4 + i;
            const int row = g * 8 + rlo;
            gload16(Wbase + (size_t)row * K + ks + pslot * 8, smem + g * 1024);
            gload16(Abase + (size_t)row * K + ks + pslot * 8, smem + 16384 + g * 1024);
        }
        __syncthreads();   // compiler drains vmcnt(0) before barrier -> tiles ready

        // ---- compute: 2 k-halves x (8 ds_read_b128 + 16 MFMA) ----
#pragma unroll
        for (int h = 0; h < 2; ++h) {
            bf16x8 a[4], b[4];
#pragma unroll
            for (int i = 0; i < 4; ++i) {
                const int rowA = wc * 64 + i * 16 + lr;
                a[i] = *(const bf16x8*)(smem + rowA * 128 + (4 * h + kg) * 16);
                const int rowB = wr * 64 + i * 16 + lr;
                b[i] = *(const bf16x8*)(smem + 16384 + rowB * 128 + (4 * h + kg) * 16);
            }
#pragma unroll
            for (int m = 0; m < 4; ++m)
#pragma unroll
                for (int n = 0; n < 4; ++n)
                    acc[m][n] = __builtin_amdgcn_mfma_f32_16x16x32_bf16(a[m], b[n], acc[m][n], 0, 0, 0);
        }
        __syncthreads();   // all reads done before next overwrite
    }

    // ---- epilogue: bias + relu -> bf16, 8B stores, row-contiguous ----
#pragma unroll
    for (int m = 0; m < 4; ++m) {
        const float4 bv = *(const float4*)(bias + e * 512 + nb0 + wc * 64 + m * 16 + kg * 4);
#pragma unroll
        for (int n = 0; n < 4; ++n) {
            const float x0 = fmaxf(acc[m][n][0] + bv.x, 0.f);
            const float x1 = fmaxf(acc[m][n][1] + bv.y, 0.f);
            const float x2 = fmaxf(acc[m][n][2] + bv.z, 0.f);
            const float x3 = fmaxf(acc[m][n][3] + bv.w, 0.f);
            uint2 w;
            w.x = pk2bf(x0, x1);
            w.y = pk2bf(x2, x3);
            const int row = m0 + wr * 64 + n * 16 + lr;
            const int col = nb0 + wc * 64 + m * 16 + kg * 4;
            *(uint2*)(Obase + (size_t)row * 512 + col) = w;
        }
    }
}

// ---- layer 3: Mc x 32, K=512; non-swapped so fp32 stores are row-contig ----
__global__ __launch_bounds__(256, 3) void gemm_o(
    const uint16_t* __restrict__ Act,   // h2, + e*actEStride, [Mc][512]
    size_t actEStride,
    const uint16_t* __restrict__ W3t,   // [8][32][512] bf16
    const float* __restrict__ b3,       // [8][32]
    float* __restrict__ Out)            // chunk base of [B][256] fp32 (= [B][E][32])
{
    __shared__ char smem[16384 + 4096]; // Act tile [128][64k] + W3 tile [32][64k]
    const int tid = threadIdx.x, wid = tid >> 6, lane = tid & 63;
    const int kg = lane >> 4, lr = lane & 15;
    const int e  = blockIdx.x;
    const int m0 = blockIdx.z * 128;

    const uint16_t* Abase = Act + (size_t)e * actEStride + (size_t)m0 * 512;
    const uint16_t* Bbase = W3t + (size_t)e * 32 * 512;

    f32x4 acc[2][2];
#pragma unroll
    for (int i = 0; i < 2; ++i)
#pragma unroll
        for (int j = 0; j < 2; ++j) acc[i][j] = f32x4{0.f, 0.f, 0.f, 0.f};

    const int rlo = lane >> 3, pslot = lane & 7;

    for (int ks = 0; ks < 512; ks += 64) {
#pragma unroll
        for (int i = 0; i < 4; ++i) {
            const int g   = wid * 4 + i;
            const int row = g * 8 + rlo;
            gload16(Abase + (size_t)row * 512 + ks + pslot * 8, smem + g * 1024);
        }
        {   // W3 tile: 4 segs, one per wave
            const int row = wid * 8 + rlo;
            gload16(Bbase + (size_t)row * 512 + ks + pslot * 8, smem + 16384 + wid * 1024);
        }
        __syncthreads();

#pragma unroll
        for (int h = 0; h < 2; ++h) {
            bf16x8 a[2], b[2];
#pragma unroll
            for (int i = 0; i < 2; ++i) {
                const int rowA = wid * 32 + i * 16 + lr;   // wave owns 32 batch rows
                a[i] = *(const bf16x8*)(smem + rowA * 128 + (4 * h + kg) * 16);
                const int rowB = i * 16 + lr;
                b[i] = *(const bf16x8*)(smem + 16384 + rowB * 128 + (4 * h + kg) * 16);
            }
#pragma unroll
            for (int af = 0; af < 2; ++af)
#pragma unroll
                for (int bf = 0; bf < 2; ++bf)
                    acc[af][bf] = __builtin_amdgcn_mfma_f32_16x16x32_bf16(a[af], b[bf], acc[af][bf], 0, 0, 0);
        }
        __syncthreads();
    }

#pragma unroll
    for (int af = 0; af < 2; ++af)
#pragma unroll
        for (int bf = 0; bf < 2; ++bf) {
            const float bb = b3[e * 32 + bf * 16 + lr];
#pragma unroll
            for (int v = 0; v < 4; ++v) {
                const int row = m0 + wid * 32 + af * 16 + kg * 4 + v;
                Out[(size_t)row * 256 + e * 32 + bf * 16 + lr] = acc[af][bf][v] + bb;
            }
        }
}

// =====================================================================
// Fallback (round-3 fused kernel, 14.25MB ws) — only if ws too small.
// =====================================================================
template <int K, bool B_LDS>
__device__ __forceinline__ void layer128(
    const uint16_t* __restrict__ Aw, const uint16_t* __restrict__ Bg,
    const char* __restrict__ Bl, const float* __restrict__ bias,
    char* __restrict__ ldsOut, int n0, int kg, int lr, bool syncBeforeEpi) {
    f32x4 acc[8][4];
#pragma unroll
    for (int m = 0; m < 8; ++m)
#pragma unroll
        for (int n = 0; n < 4; ++n) acc[m][n] = f32x4{0.f, 0.f, 0.f, 0.f};
    auto ldA = [&](int mf, int k0) -> bf16x8 {
        return *(const bf16x8*)(Aw + (size_t)(mf * 16 + lr) * K + k0 + kg * 8);
    };
    auto ldB = [&](int nf, int k0) -> bf16x8 {
        if constexpr (B_LDS) {
            const int row = nf * 16 + lr;
            return *(const bf16x8*)(Bl + row * 1024 +
                                    ((((k0 + kg * 8) << 1)) ^ ((row & 7) << 4)));
        } else {
            return *(const bf16x8*)(Bg + (size_t)(nf * 16 + lr) * K + k0 + kg * 8);
        }
    };
    bf16x8 a0[8], b0[4], a1[8], b1[4];
#pragma unroll
    for (int i = 0; i < 8; ++i) a0[i] = ldA(i, 0);
#pragma unroll
    for (int i = 0; i < 4; ++i) b0[i] = ldB(i, 0);
#pragma unroll
    for (int k0 = 0; k0 < K; k0 += 64) {
#pragma unroll
        for (int i = 0; i < 8; ++i) a1[i] = ldA(i, k0 + 32);
#pragma unroll
        for (int i = 0; i < 4; ++i) b1[i] = ldB(i, k0 + 32);
#pragma unroll
        for (int m = 0; m < 8; ++m)
#pragma unroll
            for (int n = 0; n < 4; ++n)
                acc[m][n] = __builtin_amdgcn_mfma_f32_16x16x32_bf16(a0[m], b0[n], acc[m][n], 0, 0, 0);
        if (k0 + 64 < K) {
#pragma unroll
            for (int i = 0; i < 8; ++i) a0[i] = ldA(i, k0 + 64);
#pragma unroll
            for (int i = 0; i < 4; ++i) b0[i] = ldB(i, k0 + 64);
        }
#pragma unroll
        for (int m = 0; m < 8; ++m)
#pragma unroll
            for (int n = 0; n < 4; ++n)
                acc[m][n] = __builtin_amdgcn_mfma_f32_16x16x32_bf16(a1[m], b1[n], acc[m][n], 0, 0, 0);
    }
    if (syncBeforeEpi) __syncthreads();
#pragma unroll
    for (int mf = 0; mf < 8; ++mf) {
        const float4 bv = *(const float4*)(bias + mf * 16 + kg * 4);
#pragma unroll
        for (int nf = 0; nf < 4; ++nf) {
            float x0 = fmaxf(acc[mf][nf][0] + bv.x, 0.f);
            float x1 = fmaxf(acc[mf][nf][1] + bv.y, 0.f);
            float x2 = fmaxf(acc[mf][nf][2] + bv.z, 0.f);
            float x3 = fmaxf(acc[mf][nf][3] + bv.w, 0.f);
            uint2 w;
            w.x = pk2bf(x0, x1);
            w.y = pk2bf(x2, x3);
            const int row = nf * 16 + lr;
            const int colbyte = (n0 + mf * 16 + kg * 4) << 1;
            *(uint2*)(ldsOut + row * 1024 + (colbyte ^ ((row & 7) << 4))) = w;
        }
    }
}

__global__ __launch_bounds__(256, 2) void fused_mlp(
    const uint16_t* __restrict__ Xbf,
    const uint16_t* __restrict__ W1T, const float* __restrict__ b1,
    const uint16_t* __restrict__ W2T, const float* __restrict__ b2,
    const uint16_t* __restrict__ W3T, const float* __restrict__ b3,
    float* __restrict__ out) {
    extern __shared__ char hbuf[];
    const int tid = threadIdx.x, wid = tid >> 6, lane = tid & 63;
    const int kg = lane >> 4, lr = lane & 15;
    const int e  = blockIdx.x & 7;
    const int b0 = (blockIdx.x >> 3) * 64;
    const int n0 = wid * 128;
    layer128<256, false>(W1T + ((size_t)e * 512 + n0) * 256, Xbf + (size_t)b0 * 256,
                         nullptr, b1 + e * 512 + n0, hbuf, n0, kg, lr, false);
    __syncthreads();
    layer128<512, true>(W2T + ((size_t)e * 512 + n0) * 512, nullptr, hbuf,
                        b2 + e * 512 + n0, hbuf, n0, kg, lr, true);
    __syncthreads();
    {
        const int rowB  = wid * 16 + lr;
        const int bbyte = rowB * 1024;
        const int bswz  = (rowB & 7) << 4;
        const uint16_t* W3e = W3T + (size_t)e * 32 * 512;
        f32x4 acc[2];
        acc[0] = f32x4{0.f, 0.f, 0.f, 0.f};
        acc[1] = f32x4{0.f, 0.f, 0.f, 0.f};
#pragma unroll
        for (int k0 = 0; k0 < 512; k0 += 32) {
            bf16x8 a = *(const bf16x8*)(hbuf + bbyte + ((((k0 + kg * 8) << 1)) ^ bswz));
#pragma unroll
            for (int nf = 0; nf < 2; ++nf) {
                bf16x8 b = *(const bf16x8*)(W3e + (size_t)(nf * 16 + lr) * 512 + k0 + kg * 8);
                acc[nf] = __builtin_amdgcn_mfma_f32_16x16x32_bf16(a, b, acc[nf], 0, 0, 0);
            }
        }
#pragma unroll
        for (int nf = 0; nf < 2; ++nf) {
            const float bb = b3[e * 32 + nf * 16 + lr];
#pragma unroll
            for (int v = 0; v < 4; ++v) {
                const int row = b0 + wid * 16 + kg * 4 + v;
                out[(size_t)row * 256 + e * 32 + nf * 16 + lr] = acc[nf][v] + bb;
            }
        }
    }
}

// ---------------- host launch ----------------
extern "C" void kernel_launch(void* const* d_in, const int* in_sizes, int n_in,
                              void* d_out, int out_size, void* d_ws, size_t ws_size,
                              hipStream_t stream) {
    (void)in_sizes; (void)n_in; (void)out_size;
    const float* X  = (const float*)d_in[0];   // [16384,256]
    const float* W1 = (const float*)d_in[1];   // [8,256,512]
    const float* b1 = (const float*)d_in[2];   // [8,512]
    const float* W2 = (const float*)d_in[3];   // [8,512,512]
    const float* b2 = (const float*)d_in[4];   // [8,512]
    const float* W3 = (const float*)d_in[5];   // [8,512,32]
    const float* b3 = (const float*)d_in[6];   // [8,32]
    float* out = (float*)d_out;                // [16384,8,32]

    uint16_t* w1t = (uint16_t*)d_ws;           // [8][512][256] bf16  (2 MB)
    uint16_t* w2t = w1t + 8 * 256 * 512;       // [8][512][512] bf16  (4 MB)
    uint16_t* w3t = w2t + 8 * 512 * 512;       // [8][32][512]  bf16  (256 KB)
    uint16_t* xbf = w3t + 8 * 512 * 32;        // [16384][256]  bf16  (8 MB)
    uint16_t* h1  = xbf + (size_t)16384 * 256; // [8][Mc][512] bf16, e-major
    const size_t FIXED_BYTES = ((size_t)(8 * 256 * 512) + 8 * 512 * 512 + 8 * 32 * 512 +
                                (size_t)16384 * 256) * 2;   // 14,942,208

    // largest chunk whose e-indexed h1+h2 fit the workspace
    int Mc = 0;
    for (int cand = 16384; cand >= 2048; cand >>= 1) {
        if (ws_size >= FIXED_BYTES + (size_t)16384 * cand) { Mc = cand; break; }
    }

    dim3 blk(32, 8);
    transpose_bf16<<<dim3(512 / 32, 256 / 32, 8), blk, 0, stream>>>(W1, w1t, 256, 512);
    transpose_bf16<<<dim3(512 / 32, 512 / 32, 8), blk, 0, stream>>>(W2, w2t, 512, 512);
    transpose_bf16<<<dim3(32 / 32, 512 / 32, 8),  blk, 0, stream>>>(W3, w3t, 512, 32);
    cvt_bf16<<<4096, 256, 0, stream>>>(X, xbf, 16384 * 256 / 4);

    if (Mc > 0) {
        uint16_t* h2 = h1 + (size_t)8 * Mc * 512;
        const size_t eStr = (size_t)Mc * 512;
        for (int c0 = 0; c0 < 16384; c0 += Mc) {
            gemm_h<256><<<dim3(8, 4, Mc / 128), 256, 0, stream>>>(
                xbf + (size_t)c0 * 256, 0, w1t, b1, h1, eStr);
            gemm_h<512><<<dim3(8, 4, Mc / 128), 256, 0, stream>>>(
                h1, eStr, w2t, b2, h2, eStr);
            gemm_o<<<dim3(8, 1, Mc / 128), 256, 0, stream>>>(
                h2, eStr, w3t, b3, out + (size_t)c0 * 256);
        }
    } else {
        (void)hipFuncSetAttribute((const void*)fused_mlp,
                                  hipFuncAttributeMaxDynamicSharedMemorySize, 65536);
        fused_mlp<<<2048, 256, 65536, stream>>>(xbf, w1t, b1, w2t, b2, w3t, b3, out);
    }
}

// Round 7
// 211.989 us; speedup vs baseline: 1.4113x; 1.0076x over previous
//
#include <hip/hip_runtime.h>
#include <stdint.h>

// ---------------- types ----------------
typedef short bf16x8 __attribute__((ext_vector_type(8)));
typedef float f32x4  __attribute__((ext_vector_type(4)));

__device__ __forceinline__ uint16_t f2bf(float f) {
    uint32_t u = __float_as_uint(f);
    u += 0x7FFF + ((u >> 16) & 1);   // round-to-nearest-even
    return (uint16_t)(u >> 16);
}
__device__ __forceinline__ uint32_t pk2bf(float a, float b) {
    return (uint32_t)f2bf(a) | ((uint32_t)f2bf(b) << 16);
}

typedef __attribute__((address_space(1))) const uint32_t gu32;
typedef __attribute__((address_space(3))) uint32_t lu32;
__device__ __forceinline__ void gload16(const void* g, void* l) {
    // async global->LDS, 16B/lane; LDS dest = wave-uniform base + lane*16 (m104/m108)
    __builtin_amdgcn_global_load_lds((gu32*)g, (lu32*)l, 16, 0, 0);
}

// ---------------- prologue: fp32 -> bf16 transposed weights ----------------
__global__ void transpose_bf16(const float* __restrict__ in, uint16_t* __restrict__ out,
                               int R, int C) {
    __shared__ float t[32][33];
    const int tx = threadIdx.x, ty = threadIdx.y;
    const int r0 = blockIdx.y * 32, c0 = blockIdx.x * 32;
    const float* ine = in + (size_t)blockIdx.z * R * C;
    uint16_t* oute   = out + (size_t)blockIdx.z * R * C;
#pragma unroll
    for (int j = 0; j < 4; ++j)
        t[ty + 8 * j][tx] = ine[(size_t)(r0 + ty + 8 * j) * C + (c0 + tx)];
    __syncthreads();
#pragma unroll
    for (int j = 0; j < 4; ++j) {
        int orow = c0 + ty + 8 * j;
        int ocol = r0 + tx;
        oute[(size_t)orow * R + ocol] = f2bf(t[tx][ty + 8 * j]);
    }
}

__global__ void cvt_bf16(const float* __restrict__ in, uint16_t* __restrict__ out, int n4) {
    const int i = blockIdx.x * blockDim.x + threadIdx.x;
    if (i < n4) {
        const float4 v = ((const float4*)in)[i];
        ushort4 h;
        h.x = f2bf(v.x); h.y = f2bf(v.y); h.z = f2bf(v.z); h.w = f2bf(v.w);
        ((ushort4*)out)[i] = h;
    }
}

// =====================================================================
// m97-style GEMM, 128x128 tile, BK=64, 4 waves, LDS single-buffered via
// global_load_lds (linear dest) + BOTH-SIDES 16B-slot XOR swizzle:
//   phys_slot = logical_slot ^ (row & 7)     (involution, rule #21)
// Staging lane (rlo,pslot) writes row g*8+rlo phys-slot pslot, so the
// global source reads logical slot pslot^rlo; the fragment ds_read of
// logical slot (4h+kg) reads phys (4h+kg)^(row&7). Post-swizzle each
// 16B slot gets 4 broadcast lanes x 2 rows 1024B apart -> 2-way (free).
// Swapped MFMA: D = mfma(A=W frag [n][k], B=act frag [m][k])
//   -> D col(lane&15)=batch row, row(kg*4+v)=out col.
// =====================================================================
template <int K>
__global__ __launch_bounds__(256, 4) void gemm_h(
    const uint16_t* __restrict__ Act,   // activations, + e*actEStride, [Mc][K]
    size_t actEStride,                  // 0 when activations shared across e (layer 1)
    const uint16_t* __restrict__ Wt,    // [8][512][K] bf16 (n-major, k-contig)
    const float* __restrict__ bias,     // [8][512]
    uint16_t* __restrict__ Out,         // + e*outEStride, [Mc][512] bf16 (relu'd)
    size_t outEStride)
{
    __shared__ char smem[32768];        // [0,16K): W tile [128][64k]; [16K,32K): Act tile
    const int tid = threadIdx.x, wid = tid >> 6, lane = tid & 63;
    const int kg = lane >> 4, lr = lane & 15;
    const int e   = blockIdx.x;         // 0..7 -> XCD round-robin pins e's weights/slabs
    const int nb0 = blockIdx.y * 128;
    const int m0  = blockIdx.z * 128;   // chunk-relative batch row
    const int wr = wid >> 1, wc = wid & 1;

    const uint16_t* Wbase = Wt  + ((size_t)e * 512 + nb0) * K;
    const uint16_t* Abase = Act + (size_t)e * actEStride + (size_t)m0 * K;
    uint16_t* Obase       = Out + (size_t)e * outEStride;

    f32x4 acc[4][4];
#pragma unroll
    for (int m = 0; m < 4; ++m)
#pragma unroll
        for (int n = 0; n < 4; ++n) acc[m][n] = f32x4{0.f, 0.f, 0.f, 0.f};

    const int rlo = lane >> 3, pslot = lane & 7;   // staging lane map
    const int lswz = (pslot ^ rlo) * 8;            // pre-swizzled source k-offset (elems)

    for (int ks = 0; ks < K; ks += 64) {
        // ---- stage both tiles: 4 x 1KB segments per wave per tile ----
#pragma unroll
        for (int i = 0; i < 4; ++i) {
            const int g   = wid * 4 + i;
            const int row = g * 8 + rlo;           // row&7 == rlo
            gload16(Wbase + (size_t)row * K + ks + lswz, smem + g * 1024);
            gload16(Abase + (size_t)row * K + ks + lswz, smem + 16384 + g * 1024);
        }
        __syncthreads();   // compiler drains vmcnt(0) before barrier -> tiles ready

        // ---- compute: 2 k-halves x (8 ds_read_b128 + 16 MFMA) ----
#pragma unroll
        for (int h = 0; h < 2; ++h) {
            bf16x8 a[4], b[4];
#pragma unroll
            for (int i = 0; i < 4; ++i) {
                const int rowA = wc * 64 + i * 16 + lr;
                a[i] = *(const bf16x8*)(smem + rowA * 128 +
                                        (((4 * h + kg) ^ (rowA & 7)) << 4));
                const int rowB = wr * 64 + i * 16 + lr;
                b[i] = *(const bf16x8*)(smem + 16384 + rowB * 128 +
                                        (((4 * h + kg) ^ (rowB & 7)) << 4));
            }
#pragma unroll
            for (int m = 0; m < 4; ++m)
#pragma unroll
                for (int n = 0; n < 4; ++n)
                    acc[m][n] = __builtin_amdgcn_mfma_f32_16x16x32_bf16(a[m], b[n], acc[m][n], 0, 0, 0);
        }
        __syncthreads();   // all reads done before next overwrite
    }

    // ---- epilogue: bias + relu -> bf16, 8B stores, row-contiguous ----
#pragma unroll
    for (int m = 0; m < 4; ++m) {
        const float4 bv = *(const float4*)(bias + e * 512 + nb0 + wc * 64 + m * 16 + kg * 4);
#pragma unroll
        for (int n = 0; n < 4; ++n) {
            const float x0 = fmaxf(acc[m][n][0] + bv.x, 0.f);
            const float x1 = fmaxf(acc[m][n][1] + bv.y, 0.f);
            const float x2 = fmaxf(acc[m][n][2] + bv.z, 0.f);
            const float x3 = fmaxf(acc[m][n][3] + bv.w, 0.f);
            uint2 w;
            w.x = pk2bf(x0, x1);
            w.y = pk2bf(x2, x3);
            const int row = m0 + wr * 64 + n * 16 + lr;
            const int col = nb0 + wc * 64 + m * 16 + kg * 4;
            *(uint2*)(Obase + (size_t)row * 512 + col) = w;
        }
    }
}

// ---- layer 3: Mc x 32, K=512; non-swapped so fp32 stores are row-contig ----
__global__ __launch_bounds__(256, 4) void gemm_o(
    const uint16_t* __restrict__ Act,   // h2, + e*actEStride, [Mc][512]
    size_t actEStride,
    const uint16_t* __restrict__ W3t,   // [8][32][512] bf16
    const float* __restrict__ b3,       // [8][32]
    float* __restrict__ Out)            // chunk base of [B][256] fp32 (= [B][E][32])
{
    __shared__ char smem[16384 + 4096]; // Act tile [128][64k] + W3 tile [32][64k]
    const int tid = threadIdx.x, wid = tid >> 6, lane = tid & 63;
    const int kg = lane >> 4, lr = lane & 15;
    const int e  = blockIdx.x;
    const int m0 = blockIdx.z * 128;

    const uint16_t* Abase = Act + (size_t)e * actEStride + (size_t)m0 * 512;
    const uint16_t* Bbase = W3t + (size_t)e * 32 * 512;

    f32x4 acc[2][2];
#pragma unroll
    for (int i = 0; i < 2; ++i)
#pragma unroll
        for (int j = 0; j < 2; ++j) acc[i][j] = f32x4{0.f, 0.f, 0.f, 0.f};

    const int rlo = lane >> 3, pslot = lane & 7;
    const int lswz = (pslot ^ rlo) * 8;

    for (int ks = 0; ks < 512; ks += 64) {
#pragma unroll
        for (int i = 0; i < 4; ++i) {
            const int g   = wid * 4 + i;
            const int row = g * 8 + rlo;
            gload16(Abase + (size_t)row * 512 + ks + lswz, smem + g * 1024);
        }
        {   // W3 tile: 4 segs, one per wave
            const int row = wid * 8 + rlo;
            gload16(Bbase + (size_t)row * 512 + ks + lswz, smem + 16384 + wid * 1024);
        }
        __syncthreads();

#pragma unroll
        for (int h = 0; h < 2; ++h) {
            bf16x8 a[2], b[2];
#pragma unroll
            for (int i = 0; i < 2; ++i) {
                const int rowA = wid * 32 + i * 16 + lr;   // wave owns 32 batch rows
                a[i] = *(const bf16x8*)(smem + rowA * 128 +
                                        (((4 * h + kg) ^ (rowA & 7)) << 4));
                const int rowB = i * 16 + lr;
                b[i] = *(const bf16x8*)(smem + 16384 + rowB * 128 +
                                        (((4 * h + kg) ^ (rowB & 7)) << 4));
            }
#pragma unroll
            for (int af = 0; af < 2; ++af)
#pragma unroll
                for (int bf = 0; bf < 2; ++bf)
                    acc[af][bf] = __builtin_amdgcn_mfma_f32_16x16x32_bf16(a[af], b[bf], acc[af][bf], 0, 0, 0);
        }
        __syncthreads();
    }

#pragma unroll
    for (int af = 0; af < 2; ++af)
#pragma unroll
        for (int bf = 0; bf < 2; ++bf) {
            const float bb = b3[e * 32 + bf * 16 + lr];
#pragma unroll
            for (int v = 0; v < 4; ++v) {
                const int row = m0 + wid * 32 + af * 16 + kg * 4 + v;
                Out[(size_t)row * 256 + e * 32 + bf * 16 + lr] = acc[af][bf][v] + bb;
            }
        }
}

// =====================================================================
// Fallback (round-3 fused kernel, 14.25MB ws) — only if ws too small.
// =====================================================================
template <int K, bool B_LDS>
__device__ __forceinline__ void layer128(
    const uint16_t* __restrict__ Aw, const uint16_t* __restrict__ Bg,
    const char* __restrict__ Bl, const float* __restrict__ bias,
    char* __restrict__ ldsOut, int n0, int kg, int lr, bool syncBeforeEpi) {
    f32x4 acc[8][4];
#pragma unroll
    for (int m = 0; m < 8; ++m)
#pragma unroll
        for (int n = 0; n < 4; ++n) acc[m][n] = f32x4{0.f, 0.f, 0.f, 0.f};
    auto ldA = [&](int mf, int k0) -> bf16x8 {
        return *(const bf16x8*)(Aw + (size_t)(mf * 16 + lr) * K + k0 + kg * 8);
    };
    auto ldB = [&](int nf, int k0) -> bf16x8 {
        if constexpr (B_LDS) {
            const int row = nf * 16 + lr;
            return *(const bf16x8*)(Bl + row * 1024 +
                                    ((((k0 + kg * 8) << 1)) ^ ((row & 7) << 4)));
        } else {
            return *(const bf16x8*)(Bg + (size_t)(nf * 16 + lr) * K + k0 + kg * 8);
        }
    };
    bf16x8 a0[8], b0[4], a1[8], b1[4];
#pragma unroll
    for (int i = 0; i < 8; ++i) a0[i] = ldA(i, 0);
#pragma unroll
    for (int i = 0; i < 4; ++i) b0[i] = ldB(i, 0);
#pragma unroll
    for (int k0 = 0; k0 < K; k0 += 64) {
#pragma unroll
        for (int i = 0; i < 8; ++i) a1[i] = ldA(i, k0 + 32);
#pragma unroll
        for (int i = 0; i < 4; ++i) b1[i] = ldB(i, k0 + 32);
#pragma unroll
        for (int m = 0; m < 8; ++m)
#pragma unroll
            for (int n = 0; n < 4; ++n)
                acc[m][n] = __builtin_amdgcn_mfma_f32_16x16x32_bf16(a0[m], b0[n], acc[m][n], 0, 0, 0);
        if (k0 + 64 < K) {
#pragma unroll
            for (int i = 0; i < 8; ++i) a0[i] = ldA(i, k0 + 64);
#pragma unroll
            for (int i = 0; i < 4; ++i) b0[i] = ldB(i, k0 + 64);
        }
#pragma unroll
        for (int m = 0; m < 8; ++m)
#pragma unroll
            for (int n = 0; n < 4; ++n)
                acc[m][n] = __builtin_amdgcn_mfma_f32_16x16x32_bf16(a1[m], b1[n], acc[m][n], 0, 0, 0);
    }
    if (syncBeforeEpi) __syncthreads();
#pragma unroll
    for (int mf = 0; mf < 8; ++mf) {
        const float4 bv = *(const float4*)(bias + mf * 16 + kg * 4);
#pragma unroll
        for (int nf = 0; nf < 4; ++nf) {
            float x0 = fmaxf(acc[mf][nf][0] + bv.x, 0.f);
            float x1 = fmaxf(acc[mf][nf][1] + bv.y, 0.f);
            float x2 = fmaxf(acc[mf][nf][2] + bv.z, 0.f);
            float x3 = fmaxf(acc[mf][nf][3] + bv.w, 0.f);
            uint2 w;
            w.x = pk2bf(x0, x1);
            w.y = pk2bf(x2, x3);
            const int row = nf * 16 + lr;
            const int colbyte = (n0 + mf * 16 + kg * 4) << 1;
            *(uint2*)(ldsOut + row * 1024 + (colbyte ^ ((row & 7) << 4))) = w;
        }
    }
}

__global__ __launch_bounds__(256, 2) void fused_mlp(
    const uint16_t* __restrict__ Xbf,
    const uint16_t* __restrict__ W1T, const float* __restrict__ b1,
    const uint16_t* __restrict__ W2T, const float* __restrict__ b2,
    const uint16_t* __restrict__ W3T, const float* __restrict__ b3,
    float* __restrict__ out) {
    extern __shared__ char hbuf[];
    const int tid = threadIdx.x, wid = tid >> 6, lane = tid & 63;
    const int kg = lane >> 4, lr = lane & 15;
    const int e  = blockIdx.x & 7;
    const int b0 = (blockIdx.x >> 3) * 64;
    const int n0 = wid * 128;
    layer128<256, false>(W1T + ((size_t)e * 512 + n0) * 256, Xbf + (size_t)b0 * 256,
                         nullptr, b1 + e * 512 + n0, hbuf, n0, kg, lr, false);
    __syncthreads();
    layer128<512, true>(W2T + ((size_t)e * 512 + n0) * 512, nullptr, hbuf,
                        b2 + e * 512 + n0, hbuf, n0, kg, lr, true);
    __syncthreads();
    {
        const int rowB  = wid * 16 + lr;
        const int bbyte = rowB * 1024;
        const int bswz  = (rowB & 7) << 4;
        const uint16_t* W3e = W3T + (size_t)e * 32 * 512;
        f32x4 acc[2];
        acc[0] = f32x4{0.f, 0.f, 0.f, 0.f};
        acc[1] = f32x4{0.f, 0.f, 0.f, 0.f};
#pragma unroll
        for (int k0 = 0; k0 < 512; k0 += 32) {
            bf16x8 a = *(const bf16x8*)(hbuf + bbyte + ((((k0 + kg * 8) << 1)) ^ bswz));
#pragma unroll
            for (int nf = 0; nf < 2; ++nf) {
                bf16x8 b = *(const bf16x8*)(W3e + (size_t)(nf * 16 + lr) * 512 + k0 + kg * 8);
                acc[nf] = __builtin_amdgcn_mfma_f32_16x16x32_bf16(a, b, acc[nf], 0, 0, 0);
            }
        }
#pragma unroll
        for (int nf = 0; nf < 2; ++nf) {
            const float bb = b3[e * 32 + nf * 16 + lr];
#pragma unroll
            for (int v = 0; v < 4; ++v) {
                const int row = b0 + wid * 16 + kg * 4 + v;
                out[(size_t)row * 256 + e * 32 + nf * 16 + lr] = acc[nf][v] + bb;
            }
        }
    }
}

// ---------------- host launch ----------------
extern "C" void kernel_launch(void* const* d_in, const int* in_sizes, int n_in,
                              void* d_out, int out_size, void* d_ws, size_t ws_size,
                              hipStream_t stream) {
    (void)in_sizes; (void)n_in; (void)out_size;
    const float* X  = (const float*)d_in[0];   // [16384,256]
    const float* W1 = (const float*)d_in[1];   // [8,256,512]
    const float* b1 = (const float*)d_in[2];   // [8,512]
    const float* W2 = (const float*)d_in[3];   // [8,512,512]
    const float* b2 = (const float*)d_in[4];   // [8,512]
    const float* W3 = (const float*)d_in[5];   // [8,512,32]
    const float* b3 = (const float*)d_in[6];   // [8,32]
    float* out = (float*)d_out;                // [16384,8,32]

    uint16_t* w1t = (uint16_t*)d_ws;           // [8][512][256] bf16  (2 MB)
    uint16_t* w2t = w1t + 8 * 256 * 512;       // [8][512][512] bf16  (4 MB)
    uint16_t* w3t = w2t + 8 * 512 * 512;       // [8][32][512]  bf16  (256 KB)
    uint16_t* xbf = w3t + 8 * 512 * 32;        // [16384][256]  bf16  (8 MB)
    uint16_t* h1  = xbf + (size_t)16384 * 256; // [8][Mc][512] bf16, e-major
    const size_t FIXED_BYTES = ((size_t)(8 * 256 * 512) + 8 * 512 * 512 + 8 * 32 * 512 +
                                (size_t)16384 * 256) * 2;   // 14,942,208

    // largest chunk whose e-indexed h1+h2 fit the workspace
    int Mc = 0;
    for (int cand = 16384; cand >= 2048; cand >>= 1) {
        if (ws_size >= FIXED_BYTES + (size_t)16384 * cand) { Mc = cand; break; }
    }

    dim3 blk(32, 8);
    transpose_bf16<<<dim3(512 / 32, 256 / 32, 8), blk, 0, stream>>>(W1, w1t, 256, 512);
    transpose_bf16<<<dim3(512 / 32, 512 / 32, 8), blk, 0, stream>>>(W2, w2t, 512, 512);
    transpose_bf16<<<dim3(32 / 32, 512 / 32, 8),  blk, 0, stream>>>(W3, w3t, 512, 32);
    cvt_bf16<<<4096, 256, 0, stream>>>(X, xbf, 16384 * 256 / 4);

    if (Mc > 0) {
        uint16_t* h2 = h1 + (size_t)8 * Mc * 512;
        const size_t eStr = (size_t)Mc * 512;
        for (int c0 = 0; c0 < 16384; c0 += Mc) {
            gemm_h<256><<<dim3(8, 4, Mc / 128), 256, 0, stream>>>(
                xbf + (size_t)c0 * 256, 0, w1t, b1, h1, eStr);
            gemm_h<512><<<dim3(8, 4, Mc / 128), 256, 0, stream>>>(
                h1, eStr, w2t, b2, h2, eStr);
            gemm_o<<<dim3(8, 1, Mc / 128), 256, 0, stream>>>(
                h2, eStr, w3t, b3, out + (size_t)c0 * 256);
        }
    } else {
        (void)hipFuncSetAttribute((const void*)fused_mlp,
                                  hipFuncAttributeMaxDynamicSharedMemorySize, 65536);
        fused_mlp<<<2048, 256, 65536, stream>>>(xbf, w1t, b1, w2t, b2, w3t, b3, out);
    }
}

// Round 8
// 206.280 us; speedup vs baseline: 1.4504x; 1.0277x over previous
//
#include <hip/hip_runtime.h>
#include <stdint.h>

// ---------------- types ----------------
typedef short bf16x8 __attribute__((ext_vector_type(8)));
typedef float f32x4  __attribute__((ext_vector_type(4)));

__device__ __forceinline__ uint16_t f2bf(float f) {
    uint32_t u = __float_as_uint(f);
    u += 0x7FFF + ((u >> 16) & 1);   // round-to-nearest-even
    return (uint16_t)(u >> 16);
}
__device__ __forceinline__ uint32_t pk2bf(float a, float b) {
    return (uint32_t)f2bf(a) | ((uint32_t)f2bf(b) << 16);
}

typedef __attribute__((address_space(1))) const uint32_t gu32;
typedef __attribute__((address_space(3))) uint32_t lu32;
__device__ __forceinline__ void gload16(const void* g, void* l) {
    // async global->LDS, 16B/lane; LDS dest = wave-uniform base + lane*16 (m104/m108)
    __builtin_amdgcn_global_load_lds((gu32*)g, (lu32*)l, 16, 0, 0);
}

// ---------------- prologue: fp32 -> bf16 transposed weights ----------------
__global__ void transpose_bf16(const float* __restrict__ in, uint16_t* __restrict__ out,
                               int R, int C) {
    __shared__ float t[32][33];
    const int tx = threadIdx.x, ty = threadIdx.y;
    const int r0 = blockIdx.y * 32, c0 = blockIdx.x * 32;
    const float* ine = in + (size_t)blockIdx.z * R * C;
    uint16_t* oute   = out + (size_t)blockIdx.z * R * C;
#pragma unroll
    for (int j = 0; j < 4; ++j)
        t[ty + 8 * j][tx] = ine[(size_t)(r0 + ty + 8 * j) * C + (c0 + tx)];
    __syncthreads();
#pragma unroll
    for (int j = 0; j < 4; ++j) {
        int orow = c0 + ty + 8 * j;
        int ocol = r0 + tx;
        oute[(size_t)orow * R + ocol] = f2bf(t[tx][ty + 8 * j]);
    }
}

__global__ void cvt_bf16(const float* __restrict__ in, uint16_t* __restrict__ out, int n4) {
    const int i = blockIdx.x * blockDim.x + threadIdx.x;
    if (i < n4) {
        const float4 v = ((const float4*)in)[i];
        ushort4 h;
        h.x = f2bf(v.x); h.y = f2bf(v.y); h.z = f2bf(v.z); h.w = f2bf(v.w);
        ((ushort4*)out)[i] = h;
    }
}

// =====================================================================
// 128x128 tile, BK=64, 4 waves. T3-minimum 2-phase schedule (T4 counted
// vmcnt): double-buffered LDS; tile t+1's 8 global_load_lds issued BEFORE
// computing tile t; s_waitcnt vmcnt(8) waits only for the OLDER 8 loads
// so the prefetch stays in flight across the barrier. Raw s_barrier +
// asm "memory" fences replace __syncthreads (which would drain vmcnt(0)).
// Safety: a wave's ds_reads are consumed by MFMA (compiler lgkmcnt)
// before its end barrier, so re-staging buf[1-cur] after that barrier
// cannot race readers.
// Both-sides 16B-slot XOR swizzle (verified r7: conflicts == 0):
//   phys_slot = logical_slot ^ (row & 7).
// Swapped MFMA: D = mfma(A=W frag [n][k], B=act frag [m][k])
//   -> D col(lane&15)=batch row, row(kg*4+v)=out col.
// =====================================================================
template <int K>
__global__ __launch_bounds__(256, 2) void gemm_h(
    const uint16_t* __restrict__ Act,   // activations, + e*actEStride, [Mc][K]
    size_t actEStride,                  // 0 when activations shared across e (layer 1)
    const uint16_t* __restrict__ Wt,    // [8][512][K] bf16 (n-major, k-contig)
    const float* __restrict__ bias,     // [8][512]
    uint16_t* __restrict__ Out,         // + e*outEStride, [Mc][512] bf16 (relu'd)
    size_t outEStride)
{
    __shared__ char smem[65536];        // 2 phases x 32KB: [W tile 16K | Act tile 16K]
    const int tid = threadIdx.x, wid = tid >> 6, lane = tid & 63;
    const int kg = lane >> 4, lr = lane & 15;
    const int e   = blockIdx.x;         // 0..7 -> XCD round-robin pins e's weights/slabs
    const int nb0 = blockIdx.y * 128;
    const int m0  = blockIdx.z * 128;   // chunk-relative batch row
    const int wr = wid >> 1, wc = wid & 1;

    const uint16_t* Wbase = Wt  + ((size_t)e * 512 + nb0) * K;
    const uint16_t* Abase = Act + (size_t)e * actEStride + (size_t)m0 * K;
    uint16_t* Obase       = Out + (size_t)e * outEStride;

    f32x4 acc[4][4];
#pragma unroll
    for (int m = 0; m < 4; ++m)
#pragma unroll
        for (int n = 0; n < 4; ++n) acc[m][n] = f32x4{0.f, 0.f, 0.f, 0.f};

    const int rlo = lane >> 3, pslot = lane & 7;   // staging lane map
    const int lswz = (pslot ^ rlo) * 8;            // pre-swizzled source k-offset (elems)

    // issue 8 async loads for phase p, K-offset ks (4 W segs + 4 Act segs)
    auto STAGE = [&](int p, int ks) {
#pragma unroll
        for (int i = 0; i < 4; ++i) {
            const int g   = wid * 4 + i;
            const int row = g * 8 + rlo;           // row&7 == rlo
            gload16(Wbase + (size_t)row * K + ks + lswz, smem + p * 32768 + g * 1024);
            gload16(Abase + (size_t)row * K + ks + lswz, smem + p * 32768 + 16384 + g * 1024);
        }
    };

    constexpr int NT = K / 64;
    STAGE(0, 0);                         // prologue prefetch

#pragma unroll
    for (int t = 0; t < NT; ++t) {
        const int cur = t & 1;
        if (t + 1 < NT) {
            STAGE(1 - cur, (t + 1) * 64);                      // prefetch next tile
            asm volatile("s_waitcnt vmcnt(8)" ::: "memory");   // older 8 (cur) landed
        } else {
            asm volatile("s_waitcnt vmcnt(0)" ::: "memory");   // final tile: drain
        }
        __builtin_amdgcn_s_barrier();    // all waves' cur-tile segments visible
        asm volatile("" ::: "memory");

        const char* sW = smem + cur * 32768;
        const char* sA = sW + 16384;
#pragma unroll
        for (int h = 0; h < 2; ++h) {
            bf16x8 a[4], b[4];
#pragma unroll
            for (int i = 0; i < 4; ++i) {
                const int rowA = wc * 64 + i * 16 + lr;
                a[i] = *(const bf16x8*)(sW + rowA * 128 +
                                        (((4 * h + kg) ^ (rowA & 7)) << 4));
                const int rowB = wr * 64 + i * 16 + lr;
                b[i] = *(const bf16x8*)(sA + rowB * 128 +
                                        (((4 * h + kg) ^ (rowB & 7)) << 4));
            }
#pragma unroll
            for (int m = 0; m < 4; ++m)
#pragma unroll
                for (int n = 0; n < 4; ++n)
                    acc[m][n] = __builtin_amdgcn_mfma_f32_16x16x32_bf16(a[m], b[n], acc[m][n], 0, 0, 0);
        }
        asm volatile("s_waitcnt lgkmcnt(0)" ::: "memory");     // reads retired
        __builtin_amdgcn_s_barrier();    // safe to re-stage buf[1-cur] next iter
        asm volatile("" ::: "memory");
    }

    // ---- epilogue: bias + relu -> bf16, 8B stores, row-contiguous ----
#pragma unroll
    for (int m = 0; m < 4; ++m) {
        const float4 bv = *(const float4*)(bias + e * 512 + nb0 + wc * 64 + m * 16 + kg * 4);
#pragma unroll
        for (int n = 0; n < 4; ++n) {
            const float x0 = fmaxf(acc[m][n][0] + bv.x, 0.f);
            const float x1 = fmaxf(acc[m][n][1] + bv.y, 0.f);
            const float x2 = fmaxf(acc[m][n][2] + bv.z, 0.f);
            const float x3 = fmaxf(acc[m][n][3] + bv.w, 0.f);
            uint2 w;
            w.x = pk2bf(x0, x1);
            w.y = pk2bf(x2, x3);
            const int row = m0 + wr * 64 + n * 16 + lr;
            const int col = nb0 + wc * 64 + m * 16 + kg * 4;
            *(uint2*)(Obase + (size_t)row * 512 + col) = w;
        }
    }
}

// ---- layer 3: Mc x 32, K=512; same 2-phase schedule, 5 loads/stage ----
__global__ __launch_bounds__(256, 4) void gemm_o(
    const uint16_t* __restrict__ Act,   // h2, + e*actEStride, [Mc][512]
    size_t actEStride,
    const uint16_t* __restrict__ W3t,   // [8][32][512] bf16
    const float* __restrict__ b3,       // [8][32]
    float* __restrict__ Out)            // chunk base of [B][256] fp32 (= [B][E][32])
{
    __shared__ char smem[40960];        // 2 phases x 20KB: [Act 16K | W3 4K]
    const int tid = threadIdx.x, wid = tid >> 6, lane = tid & 63;
    const int kg = lane >> 4, lr = lane & 15;
    const int e  = blockIdx.x;
    const int m0 = blockIdx.z * 128;

    const uint16_t* Abase = Act + (size_t)e * actEStride + (size_t)m0 * 512;
    const uint16_t* Bbase = W3t + (size_t)e * 32 * 512;

    f32x4 acc[2][2];
#pragma unroll
    for (int i = 0; i < 2; ++i)
#pragma unroll
        for (int j = 0; j < 2; ++j) acc[i][j] = f32x4{0.f, 0.f, 0.f, 0.f};

    const int rlo = lane >> 3, pslot = lane & 7;
    const int lswz = (pslot ^ rlo) * 8;

    auto STAGE = [&](int p, int ks) {
#pragma unroll
        for (int i = 0; i < 4; ++i) {
            const int g   = wid * 4 + i;
            const int row = g * 8 + rlo;
            gload16(Abase + (size_t)row * 512 + ks + lswz, smem + p * 20480 + g * 1024);
        }
        const int row = wid * 8 + rlo;
        gload16(Bbase + (size_t)row * 512 + ks + lswz, smem + p * 20480 + 16384 + wid * 1024);
    };

    STAGE(0, 0);

#pragma unroll
    for (int t = 0; t < 8; ++t) {
        const int cur = t & 1;
        if (t + 1 < 8) {
            STAGE(1 - cur, (t + 1) * 64);
            asm volatile("s_waitcnt vmcnt(5)" ::: "memory");
        } else {
            asm volatile("s_waitcnt vmcnt(0)" ::: "memory");
        }
        __builtin_amdgcn_s_barrier();
        asm volatile("" ::: "memory");

        const char* sA = smem + cur * 20480;
        const char* sB = sA + 16384;
#pragma unroll
        for (int h = 0; h < 2; ++h) {
            bf16x8 a[2], b[2];
#pragma unroll
            for (int i = 0; i < 2; ++i) {
                const int rowA = wid * 32 + i * 16 + lr;   // wave owns 32 batch rows
                a[i] = *(const bf16x8*)(sA + rowA * 128 +
                                        (((4 * h + kg) ^ (rowA & 7)) << 4));
                const int rowB = i * 16 + lr;
                b[i] = *(const bf16x8*)(sB + rowB * 128 +
                                        (((4 * h + kg) ^ (rowB & 7)) << 4));
            }
#pragma unroll
            for (int af = 0; af < 2; ++af)
#pragma unroll
                for (int bf = 0; bf < 2; ++bf)
                    acc[af][bf] = __builtin_amdgcn_mfma_f32_16x16x32_bf16(a[af], b[bf], acc[af][bf], 0, 0, 0);
        }
        asm volatile("s_waitcnt lgkmcnt(0)" ::: "memory");
        __builtin_amdgcn_s_barrier();
        asm volatile("" ::: "memory");
    }

#pragma unroll
    for (int af = 0; af < 2; ++af)
#pragma unroll
        for (int bf = 0; bf < 2; ++bf) {
            const float bb = b3[e * 32 + bf * 16 + lr];
#pragma unroll
            for (int v = 0; v < 4; ++v) {
                const int row = m0 + wid * 32 + af * 16 + kg * 4 + v;
                Out[(size_t)row * 256 + e * 32 + bf * 16 + lr] = acc[af][bf][v] + bb;
            }
        }
}

// =====================================================================
// Fallback (round-3 fused kernel, 14.25MB ws) — only if ws too small.
// =====================================================================
template <int K, bool B_LDS>
__device__ __forceinline__ void layer128(
    const uint16_t* __restrict__ Aw, const uint16_t* __restrict__ Bg,
    const char* __restrict__ Bl, const float* __restrict__ bias,
    char* __restrict__ ldsOut, int n0, int kg, int lr, bool syncBeforeEpi) {
    f32x4 acc[8][4];
#pragma unroll
    for (int m = 0; m < 8; ++m)
#pragma unroll
        for (int n = 0; n < 4; ++n) acc[m][n] = f32x4{0.f, 0.f, 0.f, 0.f};
    auto ldA = [&](int mf, int k0) -> bf16x8 {
        return *(const bf16x8*)(Aw + (size_t)(mf * 16 + lr) * K + k0 + kg * 8);
    };
    auto ldB = [&](int nf, int k0) -> bf16x8 {
        if constexpr (B_LDS) {
            const int row = nf * 16 + lr;
            return *(const bf16x8*)(Bl + row * 1024 +
                                    ((((k0 + kg * 8) << 1)) ^ ((row & 7) << 4)));
        } else {
            return *(const bf16x8*)(Bg + (size_t)(nf * 16 + lr) * K + k0 + kg * 8);
        }
    };
    bf16x8 a0[8], b0[4], a1[8], b1[4];
#pragma unroll
    for (int i = 0; i < 8; ++i) a0[i] = ldA(i, 0);
#pragma unroll
    for (int i = 0; i < 4; ++i) b0[i] = ldB(i, 0);
#pragma unroll
    for (int k0 = 0; k0 < K; k0 += 64) {
#pragma unroll
        for (int i = 0; i < 8; ++i) a1[i] = ldA(i, k0 + 32);
#pragma unroll
        for (int i = 0; i < 4; ++i) b1[i] = ldB(i, k0 + 32);
#pragma unroll
        for (int m = 0; m < 8; ++m)
#pragma unroll
            for (int n = 0; n < 4; ++n)
                acc[m][n] = __builtin_amdgcn_mfma_f32_16x16x32_bf16(a0[m], b0[n], acc[m][n], 0, 0, 0);
        if (k0 + 64 < K) {
#pragma unroll
            for (int i = 0; i < 8; ++i) a0[i] = ldA(i, k0 + 64);
#pragma unroll
            for (int i = 0; i < 4; ++i) b0[i] = ldB(i, k0 + 64);
        }
#pragma unroll
        for (int m = 0; m < 8; ++m)
#pragma unroll
            for (int n = 0; n < 4; ++n)
                acc[m][n] = __builtin_amdgcn_mfma_f32_16x16x32_bf16(a1[m], b1[n], acc[m][n], 0, 0, 0);
    }
    if (syncBeforeEpi) __syncthreads();
#pragma unroll
    for (int mf = 0; mf < 8; ++mf) {
        const float4 bv = *(const float4*)(bias + mf * 16 + kg * 4);
#pragma unroll
        for (int nf = 0; nf < 4; ++nf) {
            float x0 = fmaxf(acc[mf][nf][0] + bv.x, 0.f);
            float x1 = fmaxf(acc[mf][nf][1] + bv.y, 0.f);
            float x2 = fmaxf(acc[mf][nf][2] + bv.z, 0.f);
            float x3 = fmaxf(acc[mf][nf][3] + bv.w, 0.f);
            uint2 w;
            w.x = pk2bf(x0, x1);
            w.y = pk2bf(x2, x3);
            const int row = nf * 16 + lr;
            const int colbyte = (n0 + mf * 16 + kg * 4) << 1;
            *(uint2*)(ldsOut + row * 1024 + (colbyte ^ ((row & 7) << 4))) = w;
        }
    }
}

__global__ __launch_bounds__(256, 2) void fused_mlp(
    const uint16_t* __restrict__ Xbf,
    const uint16_t* __restrict__ W1T, const float* __restrict__ b1,
    const uint16_t* __restrict__ W2T, const float* __restrict__ b2,
    const uint16_t* __restrict__ W3T, const float* __restrict__ b3,
    float* __restrict__ out) {
    extern __shared__ char hbuf[];
    const int tid = threadIdx.x, wid = tid >> 6, lane = tid & 63;
    const int kg = lane >> 4, lr = lane & 15;
    const int e  = blockIdx.x & 7;
    const int b0 = (blockIdx.x >> 3) * 64;
    const int n0 = wid * 128;
    layer128<256, false>(W1T + ((size_t)e * 512 + n0) * 256, Xbf + (size_t)b0 * 256,
                         nullptr, b1 + e * 512 + n0, hbuf, n0, kg, lr, false);
    __syncthreads();
    layer128<512, true>(W2T + ((size_t)e * 512 + n0) * 512, nullptr, hbuf,
                        b2 + e * 512 + n0, hbuf, n0, kg, lr, true);
    __syncthreads();
    {
        const int rowB  = wid * 16 + lr;
        const int bbyte = rowB * 1024;
        const int bswz  = (rowB & 7) << 4;
        const uint16_t* W3e = W3T + (size_t)e * 32 * 512;
        f32x4 acc[2];
        acc[0] = f32x4{0.f, 0.f, 0.f, 0.f};
        acc[1] = f32x4{0.f, 0.f, 0.f, 0.f};
#pragma unroll
        for (int k0 = 0; k0 < 512; k0 += 32) {
            bf16x8 a = *(const bf16x8*)(hbuf + bbyte + ((((k0 + kg * 8) << 1)) ^ bswz));
#pragma unroll
            for (int nf = 0; nf < 2; ++nf) {
                bf16x8 b = *(const bf16x8*)(W3e + (size_t)(nf * 16 + lr) * 512 + k0 + kg * 8);
                acc[nf] = __builtin_amdgcn_mfma_f32_16x16x32_bf16(a, b, acc[nf], 0, 0, 0);
            }
        }
#pragma unroll
        for (int nf = 0; nf < 2; ++nf) {
            const float bb = b3[e * 32 + nf * 16 + lr];
#pragma unroll
            for (int v = 0; v < 4; ++v) {
                const int row = b0 + wid * 16 + kg * 4 + v;
                out[(size_t)row * 256 + e * 32 + nf * 16 + lr] = acc[nf][v] + bb;
            }
        }
    }
}

// ---------------- host launch ----------------
extern "C" void kernel_launch(void* const* d_in, const int* in_sizes, int n_in,
                              void* d_out, int out_size, void* d_ws, size_t ws_size,
                              hipStream_t stream) {
    (void)in_sizes; (void)n_in; (void)out_size;
    const float* X  = (const float*)d_in[0];   // [16384,256]
    const float* W1 = (const float*)d_in[1];   // [8,256,512]
    const float* b1 = (const float*)d_in[2];   // [8,512]
    const float* W2 = (const float*)d_in[3];   // [8,512,512]
    const float* b2 = (const float*)d_in[4];   // [8,512]
    const float* W3 = (const float*)d_in[5];   // [8,512,32]
    const float* b3 = (const float*)d_in[6];   // [8,32]
    float* out = (float*)d_out;                // [16384,8,32]

    uint16_t* w1t = (uint16_t*)d_ws;           // [8][512][256] bf16  (2 MB)
    uint16_t* w2t = w1t + 8 * 256 * 512;       // [8][512][512] bf16  (4 MB)
    uint16_t* w3t = w2t + 8 * 512 * 512;       // [8][32][512]  bf16  (256 KB)
    uint16_t* xbf = w3t + 8 * 512 * 32;        // [16384][256]  bf16  (8 MB)
    uint16_t* h1  = xbf + (size_t)16384 * 256; // [8][Mc][512] bf16, e-major
    const size_t FIXED_BYTES = ((size_t)(8 * 256 * 512) + 8 * 512 * 512 + 8 * 32 * 512 +
                                (size_t)16384 * 256) * 2;   // 14,942,208

    // largest chunk whose e-indexed h1+h2 fit the workspace
    int Mc = 0;
    for (int cand = 16384; cand >= 2048; cand >>= 1) {
        if (ws_size >= FIXED_BYTES + (size_t)16384 * cand) { Mc = cand; break; }
    }

    dim3 blk(32, 8);
    transpose_bf16<<<dim3(512 / 32, 256 / 32, 8), blk, 0, stream>>>(W1, w1t, 256, 512);
    transpose_bf16<<<dim3(512 / 32, 512 / 32, 8), blk, 0, stream>>>(W2, w2t, 512, 512);
    transpose_bf16<<<dim3(32 / 32, 512 / 32, 8),  blk, 0, stream>>>(W3, w3t, 512, 32);
    cvt_bf16<<<4096, 256, 0, stream>>>(X, xbf, 16384 * 256 / 4);

    if (Mc > 0) {
        uint16_t* h2 = h1 + (size_t)8 * Mc * 512;
        const size_t eStr = (size_t)Mc * 512;
        for (int c0 = 0; c0 < 16384; c0 += Mc) {
            gemm_h<256><<<dim3(8, 4, Mc / 128), 256, 0, stream>>>(
                xbf + (size_t)c0 * 256, 0, w1t, b1, h1, eStr);
            gemm_h<512><<<dim3(8, 4, Mc / 128), 256, 0, stream>>>(
                h1, eStr, w2t, b2, h2, eStr);
            gemm_o<<<dim3(8, 1, Mc / 128), 256, 0, stream>>>(
                h2, eStr, w3t, b3, out + (size_t)c0 * 256);
        }
    } else {
        (void)hipFuncSetAttribute((const void*)fused_mlp,
                                  hipFuncAttributeMaxDynamicSharedMemorySize, 65536);
        fused_mlp<<<2048, 256, 65536, stream>>>(xbf, w1t, b1, w2t, b2, w3t, b3, out);
    }
}

// Round 9
// 205.449 us; speedup vs baseline: 1.4563x; 1.0040x over previous
//
#include <hip/hip_runtime.h>
#include <stdint.h>

// ---------------- types ----------------
typedef short bf16x8 __attribute__((ext_vector_type(8)));
typedef float f32x4  __attribute__((ext_vector_type(4)));

__device__ __forceinline__ uint16_t f2bf(float f) {
    uint32_t u = __float_as_uint(f);
    u += 0x7FFF + ((u >> 16) & 1);   // round-to-nearest-even
    return (uint16_t)(u >> 16);
}
__device__ __forceinline__ uint32_t pk2bf(float a, float b) {
    return (uint32_t)f2bf(a) | ((uint32_t)f2bf(b) << 16);
}

typedef __attribute__((address_space(1))) const uint32_t gu32;
typedef __attribute__((address_space(3))) uint32_t lu32;
__device__ __forceinline__ void gload16(const void* g, void* l) {
    // async global->LDS, 16B/lane; LDS dest = wave-uniform base + lane*16 (m104/m108)
    __builtin_amdgcn_global_load_lds((gu32*)g, (lu32*)l, 16, 0, 0);
}

// ---------------- prologue: fp32 -> bf16 transposed weights ----------------
__global__ void transpose_bf16(const float* __restrict__ in, uint16_t* __restrict__ out,
                               int R, int C) {
    __shared__ float t[32][33];
    const int tx = threadIdx.x, ty = threadIdx.y;
    const int r0 = blockIdx.y * 32, c0 = blockIdx.x * 32;
    const float* ine = in + (size_t)blockIdx.z * R * C;
    uint16_t* oute   = out + (size_t)blockIdx.z * R * C;
#pragma unroll
    for (int j = 0; j < 4; ++j)
        t[ty + 8 * j][tx] = ine[(size_t)(r0 + ty + 8 * j) * C + (c0 + tx)];
    __syncthreads();
#pragma unroll
    for (int j = 0; j < 4; ++j) {
        int orow = c0 + ty + 8 * j;
        int ocol = r0 + tx;
        oute[(size_t)orow * R + ocol] = f2bf(t[tx][ty + 8 * j]);
    }
}

__global__ void cvt_bf16(const float* __restrict__ in, uint16_t* __restrict__ out, int n4) {
    const int i = blockIdx.x * blockDim.x + threadIdx.x;
    if (i < n4) {
        const float4 v = ((const float4*)in)[i];
        ushort4 h;
        h.x = f2bf(v.x); h.y = f2bf(v.y); h.z = f2bf(v.z); h.w = f2bf(v.w);
        ((ushort4*)out)[i] = h;
    }
}

// =====================================================================
// 256x256 tile, BK=64, 8 waves (wave grid 2 batch x 4 ncol; per-wave
// 128 batch x 64 ncol = 8x4 frags, 128 acc VGPR). LDS-read-bound fix:
// 24KB LDS reads per 64 MFMA per wave (0.375 KB/MFMA vs 0.5 at 64x64).
// Schedule = round-8-proven 2-phase counted vmcnt: STAGE(t+1) issued a
// full K-step (~1400cy) before its vmcnt gate -> HBM latency hidden;
// never drains mid-loop. LDS 2 x (W 32K + Act 32K) = 128KB dynamic.
// Both-sides 16B-slot XOR swizzle (verified r7: conflicts == 0):
//   phys_slot = logical_slot ^ (row & 7); staging lane map identical.
// Swapped MFMA: D = mfma(A=W frag [n][k], B=act frag [m][k])
//   -> D col(lane&15)=batch row, row(kg*4+v)=out col.
// Grid (8e, 2, Mc/256): linear%8 == e -> each ensemble's weights pinned
// to one XCD's L2 (W2 e-slice 512KB << 4MB).
// =====================================================================
template <int K>
__global__ __launch_bounds__(512, 1) void gemm256(
    const uint16_t* __restrict__ Act,   // activations, + e*actEStride, [Mc][K]
    size_t actEStride,                  // 0 when shared across e (layer 1)
    const uint16_t* __restrict__ Wt,    // [8][512][K] bf16 (n-major, k-contig)
    const float* __restrict__ bias,     // [8][512]
    uint16_t* __restrict__ Out,         // + e*outEStride, [Mc][512] bf16 (relu'd)
    size_t outEStride)
{
    extern __shared__ char smem[];      // 2 x 64KB: [W 32K | Act 32K]
    const int tid = threadIdx.x, wid = tid >> 6, lane = tid & 63;
    const int kg = lane >> 4, lr = lane & 15;
    const int e   = blockIdx.x;
    const int nb0 = blockIdx.y * 256;
    const int m0  = blockIdx.z * 256;
    const int wm = wid >> 2, wn = wid & 3;

    const uint16_t* Wbase = Wt  + ((size_t)e * 512 + nb0) * K;
    const uint16_t* Abase = Act + (size_t)e * actEStride + (size_t)m0 * K;
    uint16_t* Obase       = Out + (size_t)e * outEStride;

    f32x4 acc[8][4];
#pragma unroll
    for (int b = 0; b < 8; ++b)
#pragma unroll
        for (int c = 0; c < 4; ++c) acc[b][c] = f32x4{0.f, 0.f, 0.f, 0.f};

    const int rlo = lane >> 3, pslot = lane & 7;   // staging lane map
    const int lswz = (pslot ^ rlo) * 8;            // pre-swizzled source k-offset

    // stage one K-tile (W 32KB + Act 32KB) into phase p: 8 instrs/wave.
    // group g covers rows g*64+wid*8+rlo (each of 256 rows exactly once);
    // dest g*8192 + wid*1024 + lane*16 -> row'*128 + pslot*16 (matches).
    auto STAGE = [&](int p, int ks) {
#pragma unroll
        for (int g = 0; g < 4; ++g) {
            const int row = g * 64 + wid * 8 + rlo;    // row&7 == rlo
            gload16(Wbase + (size_t)row * K + ks + lswz,
                    smem + p * 65536 + g * 8192 + wid * 1024);
        }
#pragma unroll
        for (int g = 0; g < 4; ++g) {
            const int row = g * 64 + wid * 8 + rlo;
            gload16(Abase + (size_t)row * K + ks + lswz,
                    smem + p * 65536 + 32768 + g * 8192 + wid * 1024);
        }
    };

    constexpr int NT = K / 64;
    STAGE(0, 0);                         // prologue prefetch

#pragma unroll
    for (int t = 0; t < NT; ++t) {
        const int cur = t & 1;
        if (t + 1 < NT) {
            STAGE(1 - cur, (t + 1) * 64);                      // prefetch next tile
            asm volatile("s_waitcnt vmcnt(8)" ::: "memory");   // older 8 (tile t) landed
        } else {
            asm volatile("s_waitcnt vmcnt(0)" ::: "memory");   // final tile: drain
        }
        __builtin_amdgcn_s_barrier();    // all waves' tile-t segments visible
        asm volatile("" ::: "memory");

        const char* sW = smem + cur * 65536;
        const char* sA = sW + 32768;
#pragma unroll
        for (int kh = 0; kh < 2; ++kh) {
            bf16x8 wf[4], af[8];
#pragma unroll
            for (int c = 0; c < 4; ++c) {
                const int row = wn * 64 + c * 16 + lr;
                wf[c] = *(const bf16x8*)(sW + row * 128 +
                                         (((kh * 4 + kg) ^ (row & 7)) << 4));
            }
#pragma unroll
            for (int b = 0; b < 8; ++b) {
                const int row = wm * 128 + b * 16 + lr;
                af[b] = *(const bf16x8*)(sA + row * 128 +
                                         (((kh * 4 + kg) ^ (row & 7)) << 4));
            }
#pragma unroll
            for (int b = 0; b < 8; ++b)
#pragma unroll
                for (int c = 0; c < 4; ++c)
                    acc[b][c] = __builtin_amdgcn_mfma_f32_16x16x32_bf16(wf[c], af[b], acc[b][c], 0, 0, 0);
        }
        asm volatile("s_waitcnt lgkmcnt(0)" ::: "memory");     // LDS reads retired
        __builtin_amdgcn_s_barrier();    // safe to re-stage buf[1-cur] next iter
        asm volatile("" ::: "memory");
    }

    // ---- epilogue: bias + relu -> bf16, 8B stores, row-contiguous ----
#pragma unroll
    for (int c = 0; c < 4; ++c) {
        const int col = nb0 + wn * 64 + c * 16 + kg * 4;
        const float4 bv = *(const float4*)(bias + e * 512 + col);
#pragma unroll
        for (int b = 0; b < 8; ++b) {
            const float x0 = fmaxf(acc[b][c][0] + bv.x, 0.f);
            const float x1 = fmaxf(acc[b][c][1] + bv.y, 0.f);
            const float x2 = fmaxf(acc[b][c][2] + bv.z, 0.f);
            const float x3 = fmaxf(acc[b][c][3] + bv.w, 0.f);
            uint2 w;
            w.x = pk2bf(x0, x1);
            w.y = pk2bf(x2, x3);
            const int row = m0 + wm * 128 + b * 16 + lr;
            *(uint2*)(Obase + (size_t)row * 512 + col) = w;
        }
    }
}

// ---- layer 3: Mc x 32, K=512; 2-phase counted vmcnt (round-8 proven) ----
__global__ __launch_bounds__(256, 4) void gemm_o(
    const uint16_t* __restrict__ Act,   // h2, + e*actEStride, [Mc][512]
    size_t actEStride,
    const uint16_t* __restrict__ W3t,   // [8][32][512] bf16
    const float* __restrict__ b3,       // [8][32]
    float* __restrict__ Out)            // chunk base of [B][256] fp32 (= [B][E][32])
{
    __shared__ char smem[40960];        // 2 phases x 20KB: [Act 16K | W3 4K]
    const int tid = threadIdx.x, wid = tid >> 6, lane = tid & 63;
    const int kg = lane >> 4, lr = lane & 15;
    const int e  = blockIdx.x;
    const int m0 = blockIdx.z * 128;

    const uint16_t* Abase = Act + (size_t)e * actEStride + (size_t)m0 * 512;
    const uint16_t* Bbase = W3t + (size_t)e * 32 * 512;

    f32x4 acc[2][2];
#pragma unroll
    for (int i = 0; i < 2; ++i)
#pragma unroll
        for (int j = 0; j < 2; ++j) acc[i][j] = f32x4{0.f, 0.f, 0.f, 0.f};

    const int rlo = lane >> 3, pslot = lane & 7;
    const int lswz = (pslot ^ rlo) * 8;

    auto STAGE = [&](int p, int ks) {
#pragma unroll
        for (int i = 0; i < 4; ++i) {
            const int g   = wid * 4 + i;
            const int row = g * 8 + rlo;
            gload16(Abase + (size_t)row * 512 + ks + lswz, smem + p * 20480 + g * 1024);
        }
        const int row = wid * 8 + rlo;
        gload16(Bbase + (size_t)row * 512 + ks + lswz, smem + p * 20480 + 16384 + wid * 1024);
    };

    STAGE(0, 0);

#pragma unroll
    for (int t = 0; t < 8; ++t) {
        const int cur = t & 1;
        if (t + 1 < 8) {
            STAGE(1 - cur, (t + 1) * 64);
            asm volatile("s_waitcnt vmcnt(5)" ::: "memory");
        } else {
            asm volatile("s_waitcnt vmcnt(0)" ::: "memory");
        }
        __builtin_amdgcn_s_barrier();
        asm volatile("" ::: "memory");

        const char* sA = smem + cur * 20480;
        const char* sB = sA + 16384;
#pragma unroll
        for (int h = 0; h < 2; ++h) {
            bf16x8 a[2], b[2];
#pragma unroll
            for (int i = 0; i < 2; ++i) {
                const int rowA = wid * 32 + i * 16 + lr;   // wave owns 32 batch rows
                a[i] = *(const bf16x8*)(sA + rowA * 128 +
                                        (((4 * h + kg) ^ (rowA & 7)) << 4));
                const int rowB = i * 16 + lr;
                b[i] = *(const bf16x8*)(sB + rowB * 128 +
                                        (((4 * h + kg) ^ (rowB & 7)) << 4));
            }
#pragma unroll
            for (int af = 0; af < 2; ++af)
#pragma unroll
                for (int bf = 0; bf < 2; ++bf)
                    acc[af][bf] = __builtin_amdgcn_mfma_f32_16x16x32_bf16(a[af], b[bf], acc[af][bf], 0, 0, 0);
        }
        asm volatile("s_waitcnt lgkmcnt(0)" ::: "memory");
        __builtin_amdgcn_s_barrier();
        asm volatile("" ::: "memory");
    }

#pragma unroll
    for (int af = 0; af < 2; ++af)
#pragma unroll
        for (int bf = 0; bf < 2; ++bf) {
            const float bb = b3[e * 32 + bf * 16 + lr];
#pragma unroll
            for (int v = 0; v < 4; ++v) {
                const int row = m0 + wid * 32 + af * 16 + kg * 4 + v;
                Out[(size_t)row * 256 + e * 32 + bf * 16 + lr] = acc[af][bf][v] + bb;
            }
        }
}

// =====================================================================
// Fallback (round-3 fused kernel, 14.25MB ws) — only if ws too small.
// =====================================================================
template <int K, bool B_LDS>
__device__ __forceinline__ void layer128(
    const uint16_t* __restrict__ Aw, const uint16_t* __restrict__ Bg,
    const char* __restrict__ Bl, const float* __restrict__ bias,
    char* __restrict__ ldsOut, int n0, int kg, int lr, bool syncBeforeEpi) {
    f32x4 acc[8][4];
#pragma unroll
    for (int m = 0; m < 8; ++m)
#pragma unroll
        for (int n = 0; n < 4; ++n) acc[m][n] = f32x4{0.f, 0.f, 0.f, 0.f};
    auto ldA = [&](int mf, int k0) -> bf16x8 {
        return *(const bf16x8*)(Aw + (size_t)(mf * 16 + lr) * K + k0 + kg * 8);
    };
    auto ldB = [&](int nf, int k0) -> bf16x8 {
        if constexpr (B_LDS) {
            const int row = nf * 16 + lr;
            return *(const bf16x8*)(Bl + row * 1024 +
                                    ((((k0 + kg * 8) << 1)) ^ ((row & 7) << 4)));
        } else {
            return *(const bf16x8*)(Bg + (size_t)(nf * 16 + lr) * K + k0 + kg * 8);
        }
    };
    bf16x8 a0[8], b0[4], a1[8], b1[4];
#pragma unroll
    for (int i = 0; i < 8; ++i) a0[i] = ldA(i, 0);
#pragma unroll
    for (int i = 0; i < 4; ++i) b0[i] = ldB(i, 0);
#pragma unroll
    for (int k0 = 0; k0 < K; k0 += 64) {
#pragma unroll
        for (int i = 0; i < 8; ++i) a1[i] = ldA(i, k0 + 32);
#pragma unroll
        for (int i = 0; i < 4; ++i) b1[i] = ldB(i, k0 + 32);
#pragma unroll
        for (int m = 0; m < 8; ++m)
#pragma unroll
            for (int n = 0; n < 4; ++n)
                acc[m][n] = __builtin_amdgcn_mfma_f32_16x16x32_bf16(a0[m], b0[n], acc[m][n], 0, 0, 0);
        if (k0 + 64 < K) {
#pragma unroll
            for (int i = 0; i < 8; ++i) a0[i] = ldA(i, k0 + 64);
#pragma unroll
            for (int i = 0; i < 4; ++i) b0[i] = ldB(i, k0 + 64);
        }
#pragma unroll
        for (int m = 0; m < 8; ++m)
#pragma unroll
            for (int n = 0; n < 4; ++n)
                acc[m][n] = __builtin_amdgcn_mfma_f32_16x16x32_bf16(a1[m], b1[n], acc[m][n], 0, 0, 0);
    }
    if (syncBeforeEpi) __syncthreads();
#pragma unroll
    for (int mf = 0; mf < 8; ++mf) {
        const float4 bv = *(const float4*)(bias + mf * 16 + kg * 4);
#pragma unroll
        for (int nf = 0; nf < 4; ++nf) {
            float x0 = fmaxf(acc[mf][nf][0] + bv.x, 0.f);
            float x1 = fmaxf(acc[mf][nf][1] + bv.y, 0.f);
            float x2 = fmaxf(acc[mf][nf][2] + bv.z, 0.f);
            float x3 = fmaxf(acc[mf][nf][3] + bv.w, 0.f);
            uint2 w;
            w.x = pk2bf(x0, x1);
            w.y = pk2bf(x2, x3);
            const int row = nf * 16 + lr;
            const int colbyte = (n0 + mf * 16 + kg * 4) << 1;
            *(uint2*)(ldsOut + row * 1024 + (colbyte ^ ((row & 7) << 4))) = w;
        }
    }
}

__global__ __launch_bounds__(256, 2) void fused_mlp(
    const uint16_t* __restrict__ Xbf,
    const uint16_t* __restrict__ W1T, const float* __restrict__ b1,
    const uint16_t* __restrict__ W2T, const float* __restrict__ b2,
    const uint16_t* __restrict__ W3T, const float* __restrict__ b3,
    float* __restrict__ out) {
    extern __shared__ char hbuf[];
    const int tid = threadIdx.x, wid = tid >> 6, lane = tid & 63;
    const int kg = lane >> 4, lr = lane & 15;
    const int e  = blockIdx.x & 7;
    const int b0 = (blockIdx.x >> 3) * 64;
    const int n0 = wid * 128;
    layer128<256, false>(W1T + ((size_t)e * 512 + n0) * 256, Xbf + (size_t)b0 * 256,
                         nullptr, b1 + e * 512 + n0, hbuf, n0, kg, lr, false);
    __syncthreads();
    layer128<512, true>(W2T + ((size_t)e * 512 + n0) * 512, nullptr, hbuf,
                        b2 + e * 512 + n0, hbuf, n0, kg, lr, true);
    __syncthreads();
    {
        const int rowB  = wid * 16 + lr;
        const int bbyte = rowB * 1024;
        const int bswz  = (rowB & 7) << 4;
        const uint16_t* W3e = W3T + (size_t)e * 32 * 512;
        f32x4 acc[2];
        acc[0] = f32x4{0.f, 0.f, 0.f, 0.f};
        acc[1] = f32x4{0.f, 0.f, 0.f, 0.f};
#pragma unroll
        for (int k0 = 0; k0 < 512; k0 += 32) {
            bf16x8 a = *(const bf16x8*)(hbuf + bbyte + ((((k0 + kg * 8) << 1)) ^ bswz));
#pragma unroll
            for (int nf = 0; nf < 2; ++nf) {
                bf16x8 b = *(const bf16x8*)(W3e + (size_t)(nf * 16 + lr) * 512 + k0 + kg * 8);
                acc[nf] = __builtin_amdgcn_mfma_f32_16x16x32_bf16(a, b, acc[nf], 0, 0, 0);
            }
        }
#pragma unroll
        for (int nf = 0; nf < 2; ++nf) {
            const float bb = b3[e * 32 + nf * 16 + lr];
#pragma unroll
            for (int v = 0; v < 4; ++v) {
                const int row = b0 + wid * 16 + kg * 4 + v;
                out[(size_t)row * 256 + e * 32 + nf * 16 + lr] = acc[nf][v] + bb;
            }
        }
    }
}

// ---------------- host launch ----------------
extern "C" void kernel_launch(void* const* d_in, const int* in_sizes, int n_in,
                              void* d_out, int out_size, void* d_ws, size_t ws_size,
                              hipStream_t stream) {
    (void)in_sizes; (void)n_in; (void)out_size;
    const float* X  = (const float*)d_in[0];   // [16384,256]
    const float* W1 = (const float*)d_in[1];   // [8,256,512]
    const float* b1 = (const float*)d_in[2];   // [8,512]
    const float* W2 = (const float*)d_in[3];   // [8,512,512]
    const float* b2 = (const float*)d_in[4];   // [8,512]
    const float* W3 = (const float*)d_in[5];   // [8,512,32]
    const float* b3 = (const float*)d_in[6];   // [8,32]
    float* out = (float*)d_out;                // [16384,8,32]

    uint16_t* w1t = (uint16_t*)d_ws;           // [8][512][256] bf16  (2 MB)
    uint16_t* w2t = w1t + 8 * 256 * 512;       // [8][512][512] bf16  (4 MB)
    uint16_t* w3t = w2t + 8 * 512 * 512;       // [8][32][512]  bf16  (256 KB)
    uint16_t* xbf = w3t + 8 * 512 * 32;        // [16384][256]  bf16  (8 MB)
    uint16_t* h1  = xbf + (size_t)16384 * 256; // [8][Mc][512] bf16, e-major
    const size_t FIXED_BYTES = ((size_t)(8 * 256 * 512) + 8 * 512 * 512 + 8 * 32 * 512 +
                                (size_t)16384 * 256) * 2;   // 14,942,208

    // largest chunk whose e-indexed h1+h2 fit the workspace
    int Mc = 0;
    for (int cand = 16384; cand >= 2048; cand >>= 1) {
        if (ws_size >= FIXED_BYTES + (size_t)16384 * cand) { Mc = cand; break; }
    }

    dim3 blk(32, 8);
    transpose_bf16<<<dim3(512 / 32, 256 / 32, 8), blk, 0, stream>>>(W1, w1t, 256, 512);
    transpose_bf16<<<dim3(512 / 32, 512 / 32, 8), blk, 0, stream>>>(W2, w2t, 512, 512);
    transpose_bf16<<<dim3(32 / 32, 512 / 32, 8),  blk, 0, stream>>>(W3, w3t, 512, 32);
    cvt_bf16<<<4096, 256, 0, stream>>>(X, xbf, 16384 * 256 / 4);

    if (Mc > 0) {
        uint16_t* h2 = h1 + (size_t)8 * Mc * 512;
        const size_t eStr = (size_t)Mc * 512;
        (void)hipFuncSetAttribute((const void*)gemm256<256>,
                                  hipFuncAttributeMaxDynamicSharedMemorySize, 131072);
        (void)hipFuncSetAttribute((const void*)gemm256<512>,
                                  hipFuncAttributeMaxDynamicSharedMemorySize, 131072);
        for (int c0 = 0; c0 < 16384; c0 += Mc) {
            gemm256<256><<<dim3(8, 2, Mc / 256), 512, 131072, stream>>>(
                xbf + (size_t)c0 * 256, 0, w1t, b1, h1, eStr);
            gemm256<512><<<dim3(8, 2, Mc / 256), 512, 131072, stream>>>(
                h1, eStr, w2t, b2, h2, eStr);
            gemm_o<<<dim3(8, 1, Mc / 128), 256, 0, stream>>>(
                h2, eStr, w3t, b3, out + (size_t)c0 * 256);
        }
    } else {
        (void)hipFuncSetAttribute((const void*)fused_mlp,
                                  hipFuncAttributeMaxDynamicSharedMemorySize, 65536);
        fused_mlp<<<2048, 256, 65536, stream>>>(xbf, w1t, b1, w2t, b2, w3t, b3, out);
    }
}